// Round 10
// baseline (261.815 us; speedup 1.0000x reference)
//
#include <hip/hip_runtime.h>
#include <math.h>

// Problem constants
#define B_DIM 2
#define T_SEQ 1024
#define C_DIM 1024
#define H_DIM 16
#define N_DIM 64
#define M_ROWS (B_DIM * T_SEQ)   // 2048

// MFMA GEMM tiling
#define GBM 64
#define GBN 64
#define GBK 64
#define LDK 88

// LDS column swizzle for GEMM tiles
#define SW(r, c) ((c) ^ (((((r) >> 3) & 3)) << 3))

typedef __attribute__((ext_vector_type(8))) short bf16x8;
typedef __attribute__((ext_vector_type(4))) float f32x4;
typedef unsigned short ushortx4 __attribute__((ext_vector_type(4)));
typedef unsigned short ushortx8 __attribute__((ext_vector_type(8)));

__device__ __forceinline__ unsigned short f2bf(float f) {
    unsigned int u = __float_as_uint(f);
    u = (u + 0x7FFFu + ((u >> 16) & 1u)) >> 16;   // RNE
    return (unsigned short)u;
}
__device__ __forceinline__ float bf2f(unsigned short h) {
    return __uint_as_float(((unsigned int)h) << 16);
}

__device__ __forceinline__ float wred64(float v) {
#pragma unroll
    for (int m = 32; m; m >>= 1) v += __shfl_xor(v, m);
    return v;
}

// ---------------- premix: all six token-shift mixes, fp32 -> bf16 ----------------
__global__ __launch_bounds__(256) void premix_kernel(
    const float* __restrict__ x,
    const float* mr, const float* mk, const float* mv,
    const float* mw, const float* ma, const float* mg,
    unsigned short* xr, unsigned short* xk, unsigned short* xv,
    unsigned short* xw, unsigned short* xa, unsigned short* xg)
{
    const int g = blockIdx.x * 256 + threadIdx.x;
    const size_t base = (size_t)g * 8;
    const int row = (int)(base >> 10);
    const int col = (int)(base & 1023);
    const int t_in = row & (T_SEQ - 1);

    const float* xp = x + (size_t)row * C_DIM + col;
    float4 a0 = *(const float4*)xp;
    float4 a1 = *(const float4*)(xp + 4);
    float4 p0 = make_float4(0.f, 0.f, 0.f, 0.f), p1 = p0;
    if (t_in > 0) {
        p0 = *(const float4*)(xp - C_DIM);
        p1 = *(const float4*)(xp - C_DIM + 4);
    }
    const float d0x = p0.x - a0.x, d0y = p0.y - a0.y, d0z = p0.z - a0.z, d0w = p0.w - a0.w;
    const float d1x = p1.x - a1.x, d1y = p1.y - a1.y, d1z = p1.z - a1.z, d1w = p1.w - a1.w;

    const float* ms[6] = {mr, mk, mv, mw, ma, mg};
    unsigned short* outs[6] = {xr, xk, xv, xw, xa, xg};
#pragma unroll
    for (int i = 0; i < 6; ++i) {
        const float4 m0 = *(const float4*)(ms[i] + col);
        const float4 m1 = *(const float4*)(ms[i] + col + 4);
        ushortx8 o;
        o[0] = f2bf(fmaf(d0x, m0.x, a0.x));
        o[1] = f2bf(fmaf(d0y, m0.y, a0.y));
        o[2] = f2bf(fmaf(d0z, m0.z, a0.z));
        o[3] = f2bf(fmaf(d0w, m0.w, a0.w));
        o[4] = f2bf(fmaf(d1x, m1.x, a1.x));
        o[5] = f2bf(fmaf(d1y, m1.y, a1.y));
        o[6] = f2bf(fmaf(d1z, m1.z, a1.z));
        o[7] = f2bf(fmaf(d1w, m1.w, a1.w));
        *(ushortx8*)(outs[i] + base) = o;
    }
}

// ---------------- single weight transpose (W_o, 1024x1024) ----------------
__global__ __launch_bounds__(256) void wtrans_kernel(
    const float* __restrict__ W, unsigned short* __restrict__ WT)
{
    __shared__ float tile[32][33];
    const int tx = threadIdx.x, ty = threadIdx.y;
    const int n0 = blockIdx.x * 32, k0 = blockIdx.y * 32;
#pragma unroll
    for (int i = 0; i < 4; ++i)
        tile[ty + i * 8][tx] = W[(size_t)(k0 + ty + i * 8) * 1024 + n0 + tx];
    __syncthreads();
#pragma unroll
    for (int i = 0; i < 4; ++i)
        WT[(size_t)(n0 + ty + i * 8) * 1024 + k0 + tx] = f2bf(tile[tx][ty + i * 8]);
}

// ---------------- batched transpose+convert: W_k, W_v, W_r + 8 small ----------------
__global__ __launch_bounds__(256) void trans_all_kernel(
    const float* Wk, const float* Wv, const float* Wr,
    const float* w1p, const float* a1p, const float* v1p, const float* g1p,
    const float* a2p, const float* v2p, const float* g2p, const float* w2p,
    unsigned short* wtA, unsigned short* wtB, unsigned short* wtC,
    unsigned short* wt_w1, unsigned short* wt_a1, unsigned short* wt_v1,
    unsigned short* wt_g1, unsigned short* wt_a2, unsigned short* wt_v2,
    unsigned short* wt_g2, unsigned short* wt_w2)
{
    __shared__ float tile[32][33];
    const int bid = blockIdx.x;
    const float* W; unsigned short* WT; int K, N, t0;
    if      (bid < 1024) { W = Wk;  WT = wtA;   K = 1024; N = 1024; t0 = 0;    }
    else if (bid < 2048) { W = Wv;  WT = wtB;   K = 1024; N = 1024; t0 = 1024; }
    else if (bid < 3072) { W = Wr;  WT = wtC;   K = 1024; N = 1024; t0 = 2048; }
    else if (bid < 3136) { W = w1p; WT = wt_w1; K = 1024; N = 64;   t0 = 3072; }
    else if (bid < 3200) { W = a1p; WT = wt_a1; K = 1024; N = 64;   t0 = 3136; }
    else if (bid < 3232) { W = v1p; WT = wt_v1; K = 1024; N = 32;   t0 = 3200; }
    else if (bid < 3392) { W = g1p; WT = wt_g1; K = 1024; N = 160;  t0 = 3232; }
    else if (bid < 3456) { W = a2p; WT = wt_a2; K = 64;   N = 1024; t0 = 3392; }
    else if (bid < 3488) { W = v2p; WT = wt_v2; K = 32;   N = 1024; t0 = 3456; }
    else if (bid < 3648) { W = g2p; WT = wt_g2; K = 160;  N = 1024; t0 = 3488; }
    else                 { W = w2p; WT = wt_w2; K = 64;   N = 1024; t0 = 3648; }
    const int lt = bid - t0;
    const int ntx = N >> 5;
    const int n0 = (lt % ntx) * 32;
    const int k0 = (lt / ntx) * 32;
    const int tx = threadIdx.x, ty = threadIdx.y;
#pragma unroll
    for (int i = 0; i < 4; ++i)
        tile[ty + i * 8][tx] = W[(size_t)(k0 + ty + i * 8) * N + n0 + tx];
    __syncthreads();
#pragma unroll
    for (int i = 0; i < 4; ++i)
        WT[(size_t)(n0 + ty + i * 8) * K + k0 + tx] = f2bf(tile[tx][ty + i * 8]);
}

// ---------------- generic MFMA GEMM core (bf16 A, bf16 B^T, LDS swizzled) ----------
__device__ __forceinline__ void gemm_core(
    const unsigned short* __restrict__ Aarr, int arow_stride,
    const unsigned short* __restrict__ WT, int K, int Nc, int bn0, int bm0,
    unsigned short* outp, int ostr, int ooff,
    unsigned short* outh, int hoff, int post)
{
    __shared__ unsigned short As[GBM][LDK];
    __shared__ unsigned short Bs[GBN][LDK];

    const int tid = threadIdx.x;
    const int lane = tid & 63;
    const int wid = tid >> 6;
    const int wr = wid >> 1, wc = wid & 1;
    const int l15 = lane & 15, l4 = lane >> 4;

    const int ar = tid >> 2;
    const int as = (tid & 3) << 4;
    const int row = bm0 + ar;
    const int brn = tid >> 2;
    const int bks = (tid & 3) << 4;
    const bool bn_ok = (bn0 + brn) < Nc;

    const int ra0 = wr * 32 + l15, ra1 = wr * 32 + 16 + l15;
    const int rb0 = wc * 32 + l15, rb1 = wc * 32 + 16 + l15;

    f32x4 acc[2][2] = {};

    for (int k0 = 0; k0 < K; k0 += GBK) {
#pragma unroll
        for (int i = 0; i < 2; ++i) {
            const int kk = as + 8 * i;
            ushortx8 av = {0, 0, 0, 0, 0, 0, 0, 0};
            if (k0 + kk < K)
                av = *(const ushortx8*)(Aarr + (size_t)row * arow_stride + k0 + kk);
            *(ushortx8*)&As[ar][SW(ar, kk)] = av;
        }
#pragma unroll
        for (int i = 0; i < 2; ++i) {
            const int kk = bks + 8 * i;
            ushortx8 bv = {0, 0, 0, 0, 0, 0, 0, 0};
            if (bn_ok && (k0 + kk < K))
                bv = *(const ushortx8*)(WT + (size_t)(bn0 + brn) * K + k0 + kk);
            *(ushortx8*)&Bs[brn][SW(brn, kk)] = bv;
        }
        __syncthreads();
#pragma unroll
        for (int ks = 0; ks < 2; ++ks) {
            const int cc = ks * 32 + l4 * 8;
            bf16x8 af0 = *(const bf16x8*)&As[ra0][SW(ra0, cc)];
            bf16x8 af1 = *(const bf16x8*)&As[ra1][SW(ra1, cc)];
            bf16x8 bg0 = *(const bf16x8*)&Bs[rb0][SW(rb0, cc)];
            bf16x8 bg1 = *(const bf16x8*)&Bs[rb1][SW(rb1, cc)];
            acc[0][0] = __builtin_amdgcn_mfma_f32_16x16x32_bf16(af0, bg0, acc[0][0], 0, 0, 0);
            acc[0][1] = __builtin_amdgcn_mfma_f32_16x16x32_bf16(af0, bg1, acc[0][1], 0, 0, 0);
            acc[1][0] = __builtin_amdgcn_mfma_f32_16x16x32_bf16(af1, bg0, acc[1][0], 0, 0, 0);
            acc[1][1] = __builtin_amdgcn_mfma_f32_16x16x32_bf16(af1, bg1, acc[1][1], 0, 0, 0);
        }
        __syncthreads();
    }

#pragma unroll
    for (int fi = 0; fi < 2; ++fi)
#pragma unroll
        for (int fj = 0; fj < 2; ++fj) {
            const int ocol = bn0 + wc * 32 + fj * 16 + l15;
            if (ocol < Nc) {
#pragma unroll
                for (int p = 0; p < 4; ++p) {
                    const int orow = bm0 + wr * 32 + fi * 16 + l4 * 4 + p;
                    float v = acc[fi][fj][p];
                    if (post == 1) v = tanhf(v);
                    else if (post == 2) v = 1.0f / (1.0f + expf(-v));
                    if (outh)
                        outh[(size_t)orow * 320 + hoff + ocol] = f2bf(v);
                    else
                        outp[((size_t)orow * 1024 + ocol) * ostr + ooff] = f2bf(v);
                }
            }
        }
}

// ---------------- stage-1: 7 GEMMs in one launch ----------------
__global__ __launch_bounds__(256) void gemm_s1_kernel(
    const unsigned short* xr, const unsigned short* xk, const unsigned short* xv,
    const unsigned short* xw, const unsigned short* xa, const unsigned short* xg,
    const unsigned short* wtA, const unsigned short* wtB, const unsigned short* wtC,
    const unsigned short* wt_a1, const unsigned short* wt_v1,
    const unsigned short* wt_g1, const unsigned short* wt_w1,
    unsigned short* b_r, unsigned short* pk_bf, unsigned short* b_v,
    unsigned short* h_cat)
{
    const int nt = blockIdx.x;
    const int bm0 = blockIdx.y * GBM;
    const unsigned short* A; const unsigned short* WT;
    unsigned short* outp = nullptr; unsigned short* outh = nullptr;
    int Nc = 1024, nb = 0, ostr = 1, ooff = 0, hoff = 0, post = 0;
    if (nt < 16)      { A = xr; WT = wtC; outp = b_r; nb = nt; }
    else if (nt < 32) { A = xk; WT = wtA; outp = pk_bf; ostr = 4; ooff = 1; nb = nt - 16; }
    else if (nt < 48) { A = xv; WT = wtB; outp = b_v; nb = nt - 32; }
    else if (nt == 48){ A = xa; WT = wt_a1; outh = h_cat; hoff = 0;   Nc = 64; }
    else if (nt == 49){ A = xv; WT = wt_v1; outh = h_cat; hoff = 64;  Nc = 32; }
    else if (nt < 53) { A = xg; WT = wt_g1; outh = h_cat; hoff = 96;  Nc = 160; nb = nt - 50; post = 2; }
    else              { A = xw; WT = wt_w1; outh = h_cat; hoff = 256; Nc = 64; post = 1; }
    gemm_core(A, 1024, WT, 1024, Nc, nb * 64, bm0, outp, ostr, ooff, outh, hoff, post);
}

// ---------------- stage-2: 4 GEMMs in one launch (A = h_cat) ----------------
__global__ __launch_bounds__(256) void gemm_s2_kernel(
    const unsigned short* __restrict__ h_cat,
    const unsigned short* wt_a2, const unsigned short* wt_v2,
    const unsigned short* wt_g2, const unsigned short* wt_w2,
    unsigned short* pk_bf, unsigned short* b_g)
{
    const int g = blockIdx.x >> 4;
    const int nb = blockIdx.x & 15;
    const int bm0 = blockIdx.y * GBM;
    const unsigned short* WT;
    unsigned short* outp; int K, aoff, ostr, ooff;
    if      (g == 0) { WT = wt_a2; K = 64;  aoff = 0;   outp = pk_bf; ostr = 4; ooff = 2; }
    else if (g == 1) { WT = wt_v2; K = 32;  aoff = 64;  outp = pk_bf; ostr = 4; ooff = 3; }
    else if (g == 2) { WT = wt_g2; K = 160; aoff = 96;  outp = b_g;   ostr = 1; ooff = 0; }
    else             { WT = wt_w2; K = 64;  aoff = 256; outp = pk_bf; ostr = 4; ooff = 0; }
    gemm_core(h_cat + aoff, 320, WT, K, 1024, nb * 64, bm0, outp, ostr, ooff, nullptr, 0, 0);
}

// ---------------- final GEMM: out = y_bf @ W_o + residual (f32 out) ----------------
__global__ __launch_bounds__(256) void gemm_final_kernel(
    const unsigned short* __restrict__ Y, const unsigned short* __restrict__ WT,
    const float* __restrict__ addend, float* __restrict__ out)
{
    const int K = 1024;
    __shared__ unsigned short As[GBM][LDK];
    __shared__ unsigned short Bs[GBN][LDK];

    const int tid = threadIdx.x;
    const int lane = tid & 63;
    const int wid = tid >> 6;
    const int wr = wid >> 1, wc = wid & 1;
    const int l15 = lane & 15, l4 = lane >> 4;
    const int bm0 = blockIdx.y * GBM;
    const int bn0 = blockIdx.x * GBN;
    const int ar = tid >> 2;
    const int as = (tid & 3) << 4;
    const int row = bm0 + ar;
    const int brn = tid >> 2;
    const int bks = (tid & 3) << 4;

    const int ra0 = wr * 32 + l15, ra1 = wr * 32 + 16 + l15;
    const int rb0 = wc * 32 + l15, rb1 = wc * 32 + 16 + l15;

    f32x4 acc[2][2] = {};

    for (int k0 = 0; k0 < K; k0 += GBK) {
#pragma unroll
        for (int i = 0; i < 2; ++i) {
            const int kk = as + 8 * i;
            *(ushortx8*)&As[ar][SW(ar, kk)] =
                *(const ushortx8*)(Y + (size_t)row * 1024 + k0 + kk);
        }
#pragma unroll
        for (int i = 0; i < 2; ++i) {
            const int kk = bks + 8 * i;
            *(ushortx8*)&Bs[brn][SW(brn, kk)] =
                *(const ushortx8*)(WT + (size_t)(bn0 + brn) * K + k0 + kk);
        }
        __syncthreads();
#pragma unroll
        for (int ks = 0; ks < 2; ++ks) {
            const int cc = ks * 32 + l4 * 8;
            bf16x8 af0 = *(const bf16x8*)&As[ra0][SW(ra0, cc)];
            bf16x8 af1 = *(const bf16x8*)&As[ra1][SW(ra1, cc)];
            bf16x8 bg0 = *(const bf16x8*)&Bs[rb0][SW(rb0, cc)];
            bf16x8 bg1 = *(const bf16x8*)&Bs[rb1][SW(rb1, cc)];
            acc[0][0] = __builtin_amdgcn_mfma_f32_16x16x32_bf16(af0, bg0, acc[0][0], 0, 0, 0);
            acc[0][1] = __builtin_amdgcn_mfma_f32_16x16x32_bf16(af0, bg1, acc[0][1], 0, 0, 0);
            acc[1][0] = __builtin_amdgcn_mfma_f32_16x16x32_bf16(af1, bg0, acc[1][0], 0, 0, 0);
            acc[1][1] = __builtin_amdgcn_mfma_f32_16x16x32_bf16(af1, bg1, acc[1][1], 0, 0, 0);
        }
        __syncthreads();
    }

#pragma unroll
    for (int fi = 0; fi < 2; ++fi)
#pragma unroll
        for (int fj = 0; fj < 2; ++fj) {
            const int ocol = bn0 + wc * 32 + fj * 16 + l15;
#pragma unroll
            for (int p = 0; p < 4; ++p) {
                const int orow = bm0 + wr * 32 + fi * 16 + l4 * 4 + p;
                out[(size_t)orow * 1024 + ocol] =
                    acc[fi][fj][p] + addend[(size_t)orow * 1024 + ocol];
            }
        }
}

// ---------------- stage3: elementwise prep (in-place into pk_bf) + bonus TB ----------
// pk_bf slots: in (wl,k_lin,a_lora,v_gate) -> out (wl, ko, aa, bb)
__global__ __launch_bounds__(256) void stage3_kernel(
    unsigned short* pk_bf, unsigned short* b_v,
    const float* __restrict__ v_first, const unsigned short* __restrict__ b_r,
    const float* w0, const float* a0, const float* v0,
    const float* k_k, const float* k_a, const float* r_k,
    float* __restrict__ TB)
{
    const int gw = (blockIdx.x * blockDim.x + threadIdx.x) >> 6;
    const int lane = threadIdx.x & 63;
    const int row = gw >> 4;
    const int h = gw & 15;
    const int c = h * N_DIM + lane;
    const size_t idx = (size_t)row * C_DIM + c;

    ushortx4 raw = *(const ushortx4*)(pk_bf + idx * 4);
    const float kl = bf2f(raw.y), a_lora = bf2f(raw.z), v_gate = bf2f(raw.w);

    float kkv = kl * k_k[c];
    float ss = wred64(kkv * kkv);
    const float nrm = fmaxf(sqrtf(ss), 1e-12f);
    const float kkn = kkv / nrm;

    const float a = 1.0f / (1.0f + expf(-(a0[c] + a_lora)));

    const float sv = 1.0f / (1.0f + expf(-(v0[c] + v_gate)));
    const float vl = bf2f(b_v[idx]);
    const float v = fmaf(v_first[idx] - vl, sv, vl);

    const float ko = kl * (1.0f + (a - 1.0f) * k_a[c]);
    const float r1f = bf2f(b_r[idx]);

    b_v[idx] = f2bf(v);

    const float t3 = wred64(r1f * ko * r_k[c]);
    const int b = row >> 10, t = row & 1023;
    if (lane == 0) TB[(b * 16 + h) * 1024 + t] = t3;

    ushortx4 outpk;
    outpk.x = raw.x;            // wl unchanged
    outpk.y = f2bf(ko);
    outpk.z = f2bf(-kkn);       // aa
    outpk.w = f2bf(kkn * a);    // bb
    *(ushortx4*)(pk_bf + idx * 4) = outpk;
}

// ---------------- chunked-scan PREP: per (bh, chunk of 32 steps) ----------------
// WY transform: S_t = S_{t-1}(diag(ew_t) + aa_t bb_t^T) + v_t ko_t^T
// Produces per chunk: Gt[t][k] (o_ext map), LRt[n][k'] (low-rank state corr),
// Vc[vi][n] (state injection), Wl[n] (diag decay), Oi[t][vi] (intra output).
__global__ __launch_bounds__(256) void chunk_prep_kernel(
    const unsigned short* __restrict__ pk_bf,
    const unsigned short* __restrict__ b_r,
    const unsigned short* __restrict__ b_v,
    const float* __restrict__ w0,
    unsigned short* __restrict__ Gt, unsigned short* __restrict__ LRt,
    float* __restrict__ Vc, float* __restrict__ Wl,
    unsigned short* __restrict__ Oi)
{
    __shared__ float W32[32][65];
    __shared__ float tA[32][65];          // aa -> Atilde (a*Wm1)
    __shared__ float tB[32][65];          // bb -> Btilde (b/W)
    __shared__ unsigned short tK[32][66]; // ko -> Khat (k/W) -> Ktilde
    __shared__ unsigned short tR[32][66]; // r -> Rtilde (r*W)
    __shared__ float EWZ[2112];           // ew[t*64+n] -> Z[n*33+i]
    __shared__ float cg[32][33];
    __shared__ float dg[32][33];          // d -> Dhat (in place)
    __shared__ float eg[32][33];
    __shared__ float fg[32][33];          // Agram -> f (in place)
    __shared__ unsigned short Vl[32][66];

    const int tid = threadIdx.x;
    const int lane = tid & 63;
    const int w = tid >> 6;
    const int bhc = blockIdx.x;
    const int bh = bhc >> 5, c = bhc & 31;
    const int b = bh >> 4, h = bh & 15;

    // ---- Phase A: load inputs, compute ew ----
    const float w0c = w0[h * 64 + lane];
#pragma unroll
    for (int q = 0; q < 8; ++q) {
        const int tq = w * 8 + q;
        const int row = b * 1024 + c * 32 + tq;
        const size_t gi = (size_t)row * 1024 + h * 64 + lane;
        ushortx4 pk = *(const ushortx4*)(pk_bf + gi * 4);
        const float u = w0c + bf2f(pk.x);
        const float lnw = -log1pf(expf(-u)) - 0.5f;
        const float ew = expf(-expf(lnw));
        EWZ[tq * 64 + lane] = ew;
        tA[tq][lane] = bf2f(pk.z);
        tB[tq][lane] = bf2f(pk.w);
        tK[tq][lane] = pk.y;
        tR[tq][lane] = b_r[gi];
        Vl[tq][lane] = b_v[gi];
    }
    __syncthreads();

    // ---- Phase B: cumprod of decays (wave 0) ----
    if (w == 0) {
        float run = 1.0f;
        for (int t = 0; t < 32; ++t) {
            run *= EWZ[t * 64 + lane];
            W32[t][lane] = run;
        }
    }
    __syncthreads();

    // ---- Phase C: tildes (in place) ----
#pragma unroll
    for (int q = 0; q < 8; ++q) {
        const int tq = w * 8 + q;
        const float Wt = W32[tq][lane];
        const float Wm1 = (tq == 0) ? 1.0f : W32[tq - 1][lane];
        const float iw = 1.0f / Wt;
        tA[tq][lane] *= Wm1;
        tB[tq][lane] *= iw;
        tK[tq][lane] = f2bf(bf2f(tK[tq][lane]) * iw);
        tR[tq][lane] = f2bf(bf2f(tR[tq][lane]) * Wt);
    }
    __syncthreads();

    // ---- Phase D: Gram matrices (one per wave) ----
    {
        const int a_ = lane >> 1;
        const int bbase = (lane & 1) * 16;
        float acc[16];
#pragma unroll
        for (int p = 0; p < 16; ++p) acc[p] = 0.0f;
        if (w == 0) {          // cg[j][i] = Btilde_j . Atilde_i
            for (int n = 0; n < 64; ++n) {
                const float l1 = tB[a_][n];
#pragma unroll
                for (int p = 0; p < 16; ++p) acc[p] += l1 * tA[bbase + p][n];
            }
#pragma unroll
            for (int p = 0; p < 16; ++p) cg[a_][bbase + p] = acc[p];
        } else if (w == 1) {   // dg[i][j] = Khat_i . Atilde_j
            for (int n = 0; n < 64; ++n) {
                const float l1 = bf2f(tK[a_][n]);
#pragma unroll
                for (int p = 0; p < 16; ++p) acc[p] += l1 * tA[bbase + p][n];
            }
#pragma unroll
            for (int p = 0; p < 16; ++p) dg[a_][bbase + p] = acc[p];
        } else if (w == 2) {   // eg[i][t] = Btilde_i . Rtilde_t
            for (int n = 0; n < 64; ++n) {
                const float l1 = tB[a_][n];
#pragma unroll
                for (int p = 0; p < 16; ++p) acc[p] += l1 * bf2f(tR[bbase + p][n]);
            }
#pragma unroll
            for (int p = 0; p < 16; ++p) eg[a_][bbase + p] = acc[p];
        } else {               // fg[i][t] = Khat_i . Rtilde_t
            for (int n = 0; n < 64; ++n) {
                const float l1 = bf2f(tK[a_][n]);
#pragma unroll
                for (int p = 0; p < 16; ++p) acc[p] += l1 * bf2f(tR[bbase + p][n]);
            }
#pragma unroll
            for (int p = 0; p < 16; ++p) fg[a_][bbase + p] = acc[p];
        }
    }
    __syncthreads();

    // ---- Phase E: zero invalid triangles ----
#pragma unroll
    for (int p = 0; p < 16; ++p) {
        const int idx = lane * 16 + p;
        const int aa_ = idx >> 5, bb_ = idx & 31;
        if (w == 0) { if (aa_ >= bb_) cg[aa_][bb_] = 0.0f; }       // j<i only
        else if (w == 1) { if (bb_ <= aa_) dg[aa_][bb_] = 0.0f; }  // j>i only
        else if (w == 2) { if (aa_ > bb_) eg[aa_][bb_] = 0.0f; }   // i<=t
        else { if (aa_ > bb_) fg[aa_][bb_] = 0.0f; }               // i<=t
    }
    __syncthreads();

    // ---- Phase F: triangular recurrences ----
    if (w == 0) {
        // Z[n][i] = Atilde_i[n] + sum_{j<i} cg[j][i] Z[n][j]
        for (int i = 0; i < 32; ++i) {
            float val = tA[i][lane];
            for (int j = 0; j < i; ++j) val += cg[j][i] * EWZ[lane * 33 + j];
            EWZ[lane * 33 + i] = val;
        }
    } else if (w == 1 && lane < 32) {
        // Dhat[i][t] = d[i][t] + sum_{j<t} cg[j][t] Dhat[i][j]  (in place over dg)
        for (int t = 0; t < 32; ++t) {
            float val = dg[lane][t];
            for (int j = 0; j < t; ++j) val += cg[j][t] * dg[lane][j];
            dg[lane][t] = val;
        }
    }
    __syncthreads();

    // ---- Phase G1: f = Agram + Dhat@eg ; Ktilde = (Khat + Dhat@Btilde) * W31 ----
    {
        float fv[4];
#pragma unroll
        for (int q = 0; q < 4; ++q) {
            const int idx = tid * 4 + q;
            const int fi = idx >> 5, ft = idx & 31;
            float val = fg[fi][ft];
            for (int j = 0; j < 32; ++j) val += dg[fi][j] * eg[j][ft];
            fv[q] = val;
        }
#pragma unroll
        for (int q = 0; q < 4; ++q) {
            const int idx = tid * 4 + q;
            fg[idx >> 5][idx & 31] = fv[q];
        }
        unsigned short kv[8];
#pragma unroll
        for (int q = 0; q < 8; ++q) {
            const int idx = tid * 8 + q;
            const int ki = idx >> 6, kn = idx & 63;
            float val = bf2f(tK[ki][kn]);
            for (int j = 0; j < 32; ++j) val += dg[ki][j] * tB[j][kn];
            kv[q] = f2bf(val * W32[31][kn]);
        }
#pragma unroll
        for (int q = 0; q < 8; ++q) {
            const int idx = tid * 8 + q;
            tK[idx >> 6][idx & 63] = kv[q];
        }
    }
    __syncthreads();

    // ---- Phase G2: global outputs ----
    const size_t cb2048 = (size_t)bhc * 2048;
    const size_t cb4096 = (size_t)bhc * 4096;
#pragma unroll
    for (int q = 0; q < 8; ++q) {       // Gt[t][n] = Rtilde + Z@eg
        const int idx = tid * 8 + q;
        const int t = idx >> 6, n = idx & 63;
        float val = bf2f(tR[t][n]);
        for (int i = 0; i < 32; ++i) val += EWZ[n * 33 + i] * eg[i][t];
        Gt[cb2048 + t * 64 + n] = f2bf(val);
    }
#pragma unroll
    for (int q = 0; q < 16; ++q) {      // LRt[n][k'] = W31[n] * sum_i Z[k'][i] Btilde[i][n]
        const int idx = tid * 16 + q;
        const int n = idx >> 6, k = idx & 63;
        float val = 0.0f;
        for (int i = 0; i < 32; ++i) val += EWZ[k * 33 + i] * tB[i][n];
        LRt[cb4096 + n * 64 + k] = f2bf(val * W32[31][n]);
    }
#pragma unroll
    for (int q = 0; q < 8; ++q) {       // Oi[t][vi] = sum_i v_i[vi] f[i][t]
        const int idx = tid * 8 + q;
        const int t = idx >> 6, vi = idx & 63;
        float val = 0.0f;
        for (int i = 0; i < 32; ++i) val += bf2f(Vl[i][vi]) * fg[i][t];
        Oi[cb2048 + t * 64 + vi] = f2bf(val);
    }
#pragma unroll
    for (int q = 0; q < 16; ++q) {      // Vc[vi][n] = sum_i v_i[vi] Ktilde[i][n]
        const int idx = tid * 16 + q;
        const int vi = idx >> 6, n = idx & 63;
        float val = 0.0f;
        for (int i = 0; i < 32; ++i) val += bf2f(Vl[i][vi]) * bf2f(tK[i][n]);
        Vc[cb4096 + vi * 64 + n] = val;
    }
    if (tid < 64) Wl[(size_t)bhc * 64 + tid] = W32[31][tid];
}

// ---------------- chunked-scan SEQ: 32 blocks (one per bh), MFMA ----------------
// Wave w owns S rows [w*16, w*16+16). Master S f32 in C/D layout:
// sC[nt][p] = S[w*16 + (l>>4)*4 + p][nt*16 + (l&15)]
__global__ __launch_bounds__(256) void chunk_seq_kernel(
    const unsigned short* __restrict__ Gt, const unsigned short* __restrict__ LRt,
    const float* __restrict__ Vc, const float* __restrict__ Wl,
    const unsigned short* __restrict__ Oi, unsigned short* __restrict__ o)
{
    __shared__ unsigned short Sst[4][16][80];
    const int tid = threadIdx.x, lane = tid & 63, w = tid >> 6;
    const int bh = blockIdx.x;
    const int b = bh >> 4, h = bh & 15;
    const int l15 = lane & 15, l4 = lane >> 4;

    f32x4 sC[4] = {};

    for (int c = 0; c < 32; ++c) {
        const size_t cb = (size_t)(bh * 32 + c);
        // master -> LDS bf16 (A-layout source)
#pragma unroll
        for (int nt = 0; nt < 4; ++nt)
#pragma unroll
            for (int p = 0; p < 4; ++p)
                Sst[w][l4 * 4 + p][nt * 16 + l15] = f2bf(sC[nt][p]);
        __syncthreads();

        bf16x8 a0 = *(const bf16x8*)&Sst[w][l15][l4 * 8];
        bf16x8 a1 = *(const bf16x8*)&Sst[w][l15][32 + l4 * 8];
        __syncthreads();

        const unsigned short* gt = Gt + cb * 2048;
        const unsigned short* lr = LRt + cb * 4096;

        // O_ext = S @ Gt  (2 t-tiles)
        f32x4 oacc[2] = {};
#pragma unroll
        for (int tt = 0; tt < 2; ++tt) {
            bf16x8 g0 = *(const bf16x8*)&gt[(tt * 16 + l15) * 64 + l4 * 8];
            bf16x8 g1 = *(const bf16x8*)&gt[(tt * 16 + l15) * 64 + 32 + l4 * 8];
            oacc[tt] = __builtin_amdgcn_mfma_f32_16x16x32_bf16(a0, g0, oacc[tt], 0, 0, 0);
            oacc[tt] = __builtin_amdgcn_mfma_f32_16x16x32_bf16(a1, g1, oacc[tt], 0, 0, 0);
        }
        // LRcorr = S @ LRt  (4 n-tiles)
        f32x4 lac[4] = {};
#pragma unroll
        for (int nt = 0; nt < 4; ++nt) {
            bf16x8 r0 = *(const bf16x8*)&lr[(nt * 16 + l15) * 64 + l4 * 8];
            bf16x8 r1 = *(const bf16x8*)&lr[(nt * 16 + l15) * 64 + 32 + l4 * 8];
            lac[nt] = __builtin_amdgcn_mfma_f32_16x16x32_bf16(a0, r0, lac[nt], 0, 0, 0);
            lac[nt] = __builtin_amdgcn_mfma_f32_16x16x32_bf16(a1, r1, lac[nt], 0, 0, 0);
        }

        // state update: S = S*Wl + LRcorr + Vc
#pragma unroll
        for (int nt = 0; nt < 4; ++nt) {
            const float wlv = Wl[cb * 64 + nt * 16 + l15];
#pragma unroll
            for (int p = 0; p < 4; ++p) {
                const int vi = w * 16 + l4 * 4 + p;
                const float vcv = Vc[cb * 4096 + (size_t)vi * 64 + nt * 16 + l15];
                sC[nt][p] = sC[nt][p] * wlv + lac[nt][p] + vcv;
            }
        }

        // o = O_ext + Oi  -> global (pack 4 consecutive vi)
#pragma unroll
        for (int tt = 0; tt < 2; ++tt) {
            const int trow = b * 1024 + c * 32 + tt * 16 + l15;
            const int vib = w * 16 + l4 * 4;
            ushortx4 oi = *(const ushortx4*)(Oi + cb * 2048 + (tt * 16 + l15) * 64 + vib);
            ushortx4 ov;
            ov.x = f2bf(oacc[tt][0] + bf2f(oi.x));
            ov.y = f2bf(oacc[tt][1] + bf2f(oi.y));
            ov.z = f2bf(oacc[tt][2] + bf2f(oi.z));
            ov.w = f2bf(oacc[tt][3] + bf2f(oi.w));
            *(ushortx4*)(o + (size_t)trow * 1024 + h * 64 + vib) = ov;
        }
    }
}

// ---------------- groupnorm + bonus + gate (bf16 in, bf16 y out) ----------------
__global__ __launch_bounds__(256) void post_kernel(
    const unsigned short* o, const unsigned short* v, const unsigned short* g,
    const float* __restrict__ TB,
    const float* ln_w, const float* ln_b,
    unsigned short* y)
{
    const int gw = (blockIdx.x * blockDim.x + threadIdx.x) >> 6;
    const int lane = threadIdx.x & 63;
    const int row = gw >> 4;
    const int h = gw & 15;
    const int c = h * N_DIM + lane;
    const size_t idx = (size_t)row * C_DIM + c;
    const int b = row >> 10;
    const int t = row & 1023;

    const float oo = bf2f(o[idx]);
    float s1 = oo, s2 = oo * oo;
#pragma unroll
    for (int m = 32; m; m >>= 1) {
        s1 += __shfl_xor(s1, m);
        s2 += __shfl_xor(s2, m);
    }
    const float mu = s1 * (1.0f / 64.0f);
    const float var = s2 * (1.0f / 64.0f) - mu * mu;
    float yv = (oo - mu) * rsqrtf(var + 0.00064f);
    yv = yv * ln_w[c] + ln_b[c];

    yv += TB[(b * 16 + h) * 1024 + t] * bf2f(v[idx]);
    y[idx] = f2bf(yv * bf2f(g[idx]));
}

extern "C" void kernel_launch(void* const* d_in, const int* in_sizes, int n_in,
                              void* d_out, int out_size, void* d_ws, size_t ws_size,
                              hipStream_t stream) {
    (void)in_sizes; (void)n_in; (void)out_size; (void)ws_size;

    const float* residual = (const float*)d_in[0];
    const float* x        = (const float*)d_in[1];
    const float* v_first  = (const float*)d_in[2];
    const float* mr = (const float*)d_in[6];
    const float* mw = (const float*)d_in[7];
    const float* mk = (const float*)d_in[8];
    const float* mv = (const float*)d_in[9];
    const float* ma = (const float*)d_in[10];
    const float* mg = (const float*)d_in[11];
    const float* w0 = (const float*)d_in[12];
    const float* w1 = (const float*)d_in[13];
    const float* w2 = (const float*)d_in[14];
    const float* a0 = (const float*)d_in[15];
    const float* a1 = (const float*)d_in[16];
    const float* a2 = (const float*)d_in[17];
    const float* v0 = (const float*)d_in[18];
    const float* v1 = (const float*)d_in[19];
    const float* v2 = (const float*)d_in[20];
    const float* g1 = (const float*)d_in[21];
    const float* g2 = (const float*)d_in[22];
    const float* k_k = (const float*)d_in[23];
    const float* k_a = (const float*)d_in[24];
    const float* r_k = (const float*)d_in[25];
    const float* W_r = (const float*)d_in[26];
    const float* W_k = (const float*)d_in[27];
    const float* W_v = (const float*)d_in[28];
    const float* W_o = (const float*)d_in[29];
    const float* ln_w = (const float*)d_in[30];
    const float* ln_b = (const float*)d_in[31];

    float* out = (float*)d_out;
    char* wsb = (char*)d_ws;

    // ---- workspace layout (bytes); max end 69,730,304 (proven safe) ----
    // premix (dead after s1):
    unsigned short* xr = (unsigned short*)(wsb + 0);
    unsigned short* xk = (unsigned short*)(wsb + 4194304);
    unsigned short* xv = (unsigned short*)(wsb + 8388608);
    unsigned short* xw = (unsigned short*)(wsb + 12582912);
    unsigned short* xa = (unsigned short*)(wsb + 16777216);
    unsigned short* xg = (unsigned short*)(wsb + 20971520);     // ends 25,165,824
    // chunk products (written by prep, after premix dead):
    float* Vc          = (float*)(wsb + 0);                     // 16 MiB
    unsigned short* Gt = (unsigned short*)(wsb + 16777216);     // 4 MiB
    unsigned short* Oi = (unsigned short*)(wsb + 20971520);     // 4 MiB
    unsigned short* pk_bf = (unsigned short*)(wsb + 25165824);  // 16 MiB (dead after prep)
    unsigned short* wtD = (unsigned short*)(wsb + 25165824);    // 2 MiB (written after prep)
    unsigned short* y_bf = (unsigned short*)(wsb + 27262976);   // 4 MiB (post output)
    unsigned short* b_r = (unsigned short*)(wsb + 41943040);
    unsigned short* b_v = (unsigned short*)(wsb + 46137344);
    unsigned short* b_o = (unsigned short*)(wsb + 50331648);
    unsigned short* b_g = (unsigned short*)(wsb + 54525952);
    unsigned short* h_cat = (unsigned short*)(wsb + 58720256);  // 1.25 MiB (dead after s2)
    unsigned short* wt_a1 = (unsigned short*)(wsb + 60293120);
    unsigned short* wt_v1 = (unsigned short*)(wsb + 60424192);
    unsigned short* wt_g1 = (unsigned short*)(wsb + 60489728);
    unsigned short* wt_a2 = (unsigned short*)(wsb + 60817408);
    unsigned short* wt_v2 = (unsigned short*)(wsb + 60948480);
    unsigned short* wt_g2 = (unsigned short*)(wsb + 61014016);
    unsigned short* wt_w1 = (unsigned short*)(wsb + 61341696);
    unsigned short* wt_w2 = (unsigned short*)(wsb + 61472768);
    unsigned short* wtA = (unsigned short*)(wsb + 61603840);    // dead after s1
    unsigned short* wtB = (unsigned short*)(wsb + 63700992);
    unsigned short* wtC = (unsigned short*)(wsb + 65798144);    // ends 67,895,296
    unsigned short* LRt = (unsigned short*)(wsb + 60030976);    // 8 MiB (prep, over dead wts)
    float* Wl = (float*)(wsb + 68419584);                       // 256 KiB -> 68,681,728
    float* TB = (float*)(wsb + 68681728);                       // 128 KiB -> 68,812,800

    const dim3 blk(256);
    const dim3 tblk(32, 8);

    // 1) premix
    premix_kernel<<<dim3(1024), blk, 0, stream>>>(
        x, mr, mk, mv, mw, ma, mg, xr, xk, xv, xw, xa, xg);

    // 2) transpose W_k, W_v, W_r + all small weights
    trans_all_kernel<<<dim3(3712), tblk, 0, stream>>>(
        W_k, W_v, W_r, w1, a1, v1, g1, a2, v2, g2, w2,
        wtA, wtB, wtC, wt_w1, wt_a1, wt_v1, wt_g1, wt_a2, wt_v2, wt_g2, wt_w2);

    // 3) stage-1: r, k, v, a1, v1, g1, w1
    gemm_s1_kernel<<<dim3(54, 32), blk, 0, stream>>>(
        xr, xk, xv, xw, xa, xg, wtA, wtB, wtC,
        wt_a1, wt_v1, wt_g1, wt_w1, b_r, pk_bf, b_v, h_cat);

    // 4) stage-2: a2, v2, g2, w2
    gemm_s2_kernel<<<dim3(64, 32), blk, 0, stream>>>(
        h_cat, wt_a2, wt_v2, wt_g2, wt_w2, pk_bf, b_g);

    // 5) stage3: elementwise prep in place + bonus
    stage3_kernel<<<dim3(8192), blk, 0, stream>>>(
        pk_bf, b_v, v_first, b_r, w0, a0, v0, k_k, k_a, r_k, TB);

    // 6) chunk prep (parallel WY transform)
    chunk_prep_kernel<<<dim3(1024), blk, 0, stream>>>(
        pk_bf, b_r, b_v, w0, Gt, LRt, Vc, Wl, Oi);

    // 7) W_o transpose (over dead pk_bf head)
    wtrans_kernel<<<dim3(32, 32), tblk, 0, stream>>>(W_o, wtD);

    // 8) sequential chunk scan (MFMA)
    chunk_seq_kernel<<<dim3(32), blk, 0, stream>>>(Gt, LRt, Vc, Wl, Oi, b_o);

    // 9) groupnorm + bonus + gate
    post_kernel<<<dim3(8192), blk, 0, stream>>>(
        b_o, b_v, b_g, TB, ln_w, ln_b, y_bf);

    // 10) output projection + residual
    gemm_final_kernel<<<dim3(16, 32), blk, 0, stream>>>(y_bf, wtD, residual, out);
}

// Round 11
// 208.334 us; speedup vs baseline: 1.2567x; 1.2567x over previous
//
#include <hip/hip_runtime.h>
#include <math.h>

// Problem constants
#define B_DIM 2
#define T_SEQ 1024
#define C_DIM 1024
#define H_DIM 16
#define N_DIM 64
#define M_ROWS (B_DIM * T_SEQ)   // 2048

// MFMA GEMM tiling
#define GBM 64
#define GBN 64
#define GBK 64
#define LDK 88

// LDS column swizzle for GEMM tiles
#define SW(r, c) ((c) ^ (((((r) >> 3) & 3)) << 3))

typedef __attribute__((ext_vector_type(8))) short bf16x8;
typedef __attribute__((ext_vector_type(4))) float f32x4;
typedef unsigned short ushortx4 __attribute__((ext_vector_type(4)));
typedef unsigned short ushortx8 __attribute__((ext_vector_type(8)));

__device__ __forceinline__ unsigned short f2bf(float f) {
    unsigned int u = __float_as_uint(f);
    u = (u + 0x7FFFu + ((u >> 16) & 1u)) >> 16;   // RNE
    return (unsigned short)u;
}
__device__ __forceinline__ float bf2f(unsigned short h) {
    return __uint_as_float(((unsigned int)h) << 16);
}

__device__ __forceinline__ float wred64(float v) {
#pragma unroll
    for (int m = 32; m; m >>= 1) v += __shfl_xor(v, m);
    return v;
}

// ---------------- premix: all six token-shift mixes, fp32 -> bf16 ----------------
__global__ __launch_bounds__(256) void premix_kernel(
    const float* __restrict__ x,
    const float* mr, const float* mk, const float* mv,
    const float* mw, const float* ma, const float* mg,
    unsigned short* xr, unsigned short* xk, unsigned short* xv,
    unsigned short* xw, unsigned short* xa, unsigned short* xg)
{
    const int g = blockIdx.x * 256 + threadIdx.x;
    const size_t base = (size_t)g * 8;
    const int row = (int)(base >> 10);
    const int col = (int)(base & 1023);
    const int t_in = row & (T_SEQ - 1);

    const float* xp = x + (size_t)row * C_DIM + col;
    float4 a0 = *(const float4*)xp;
    float4 a1 = *(const float4*)(xp + 4);
    float4 p0 = make_float4(0.f, 0.f, 0.f, 0.f), p1 = p0;
    if (t_in > 0) {
        p0 = *(const float4*)(xp - C_DIM);
        p1 = *(const float4*)(xp - C_DIM + 4);
    }
    const float d0x = p0.x - a0.x, d0y = p0.y - a0.y, d0z = p0.z - a0.z, d0w = p0.w - a0.w;
    const float d1x = p1.x - a1.x, d1y = p1.y - a1.y, d1z = p1.z - a1.z, d1w = p1.w - a1.w;

    const float* ms[6] = {mr, mk, mv, mw, ma, mg};
    unsigned short* outs[6] = {xr, xk, xv, xw, xa, xg};
#pragma unroll
    for (int i = 0; i < 6; ++i) {
        const float4 m0 = *(const float4*)(ms[i] + col);
        const float4 m1 = *(const float4*)(ms[i] + col + 4);
        ushortx8 o;
        o[0] = f2bf(fmaf(d0x, m0.x, a0.x));
        o[1] = f2bf(fmaf(d0y, m0.y, a0.y));
        o[2] = f2bf(fmaf(d0z, m0.z, a0.z));
        o[3] = f2bf(fmaf(d0w, m0.w, a0.w));
        o[4] = f2bf(fmaf(d1x, m1.x, a1.x));
        o[5] = f2bf(fmaf(d1y, m1.y, a1.y));
        o[6] = f2bf(fmaf(d1z, m1.z, a1.z));
        o[7] = f2bf(fmaf(d1w, m1.w, a1.w));
        *(ushortx8*)(outs[i] + base) = o;
    }
}

// ---------------- single weight transpose (W_o, 1024x1024) ----------------
__global__ __launch_bounds__(256) void wtrans_kernel(
    const float* __restrict__ W, unsigned short* __restrict__ WT)
{
    __shared__ float tile[32][33];
    const int tx = threadIdx.x, ty = threadIdx.y;
    const int n0 = blockIdx.x * 32, k0 = blockIdx.y * 32;
#pragma unroll
    for (int i = 0; i < 4; ++i)
        tile[ty + i * 8][tx] = W[(size_t)(k0 + ty + i * 8) * 1024 + n0 + tx];
    __syncthreads();
#pragma unroll
    for (int i = 0; i < 4; ++i)
        WT[(size_t)(n0 + ty + i * 8) * 1024 + k0 + tx] = f2bf(tile[tx][ty + i * 8]);
}

// ---------------- batched transpose+convert: W_k, W_v, W_r + 8 small ----------------
__global__ __launch_bounds__(256) void trans_all_kernel(
    const float* Wk, const float* Wv, const float* Wr,
    const float* w1p, const float* a1p, const float* v1p, const float* g1p,
    const float* a2p, const float* v2p, const float* g2p, const float* w2p,
    unsigned short* wtA, unsigned short* wtB, unsigned short* wtC,
    unsigned short* wt_w1, unsigned short* wt_a1, unsigned short* wt_v1,
    unsigned short* wt_g1, unsigned short* wt_a2, unsigned short* wt_v2,
    unsigned short* wt_g2, unsigned short* wt_w2)
{
    __shared__ float tile[32][33];
    const int bid = blockIdx.x;
    const float* W; unsigned short* WT; int K, N, t0;
    if      (bid < 1024) { W = Wk;  WT = wtA;   K = 1024; N = 1024; t0 = 0;    }
    else if (bid < 2048) { W = Wv;  WT = wtB;   K = 1024; N = 1024; t0 = 1024; }
    else if (bid < 3072) { W = Wr;  WT = wtC;   K = 1024; N = 1024; t0 = 2048; }
    else if (bid < 3136) { W = w1p; WT = wt_w1; K = 1024; N = 64;   t0 = 3072; }
    else if (bid < 3200) { W = a1p; WT = wt_a1; K = 1024; N = 64;   t0 = 3136; }
    else if (bid < 3232) { W = v1p; WT = wt_v1; K = 1024; N = 32;   t0 = 3200; }
    else if (bid < 3392) { W = g1p; WT = wt_g1; K = 1024; N = 160;  t0 = 3232; }
    else if (bid < 3456) { W = a2p; WT = wt_a2; K = 64;   N = 1024; t0 = 3392; }
    else if (bid < 3488) { W = v2p; WT = wt_v2; K = 32;   N = 1024; t0 = 3456; }
    else if (bid < 3648) { W = g2p; WT = wt_g2; K = 160;  N = 1024; t0 = 3488; }
    else                 { W = w2p; WT = wt_w2; K = 64;   N = 1024; t0 = 3648; }
    const int lt = bid - t0;
    const int ntx = N >> 5;
    const int n0 = (lt % ntx) * 32;
    const int k0 = (lt / ntx) * 32;
    const int tx = threadIdx.x, ty = threadIdx.y;
#pragma unroll
    for (int i = 0; i < 4; ++i)
        tile[ty + i * 8][tx] = W[(size_t)(k0 + ty + i * 8) * N + n0 + tx];
    __syncthreads();
#pragma unroll
    for (int i = 0; i < 4; ++i)
        WT[(size_t)(n0 + ty + i * 8) * K + k0 + tx] = f2bf(tile[tx][ty + i * 8]);
}

// ---------------- generic MFMA GEMM core (bf16 A, bf16 B^T, LDS swizzled) ----------
__device__ __forceinline__ void gemm_core(
    const unsigned short* __restrict__ Aarr, int arow_stride,
    const unsigned short* __restrict__ WT, int K, int Nc, int bn0, int bm0,
    unsigned short* outp, int ostr, int ooff,
    unsigned short* outh, int hoff, int post)
{
    __shared__ unsigned short As[GBM][LDK];
    __shared__ unsigned short Bs[GBN][LDK];

    const int tid = threadIdx.x;
    const int lane = tid & 63;
    const int wid = tid >> 6;
    const int wr = wid >> 1, wc = wid & 1;
    const int l15 = lane & 15, l4 = lane >> 4;

    const int ar = tid >> 2;
    const int as = (tid & 3) << 4;
    const int row = bm0 + ar;
    const int brn = tid >> 2;
    const int bks = (tid & 3) << 4;
    const bool bn_ok = (bn0 + brn) < Nc;

    const int ra0 = wr * 32 + l15, ra1 = wr * 32 + 16 + l15;
    const int rb0 = wc * 32 + l15, rb1 = wc * 32 + 16 + l15;

    f32x4 acc[2][2] = {};

    for (int k0 = 0; k0 < K; k0 += GBK) {
#pragma unroll
        for (int i = 0; i < 2; ++i) {
            const int kk = as + 8 * i;
            ushortx8 av = {0, 0, 0, 0, 0, 0, 0, 0};
            if (k0 + kk < K)
                av = *(const ushortx8*)(Aarr + (size_t)row * arow_stride + k0 + kk);
            *(ushortx8*)&As[ar][SW(ar, kk)] = av;
        }
#pragma unroll
        for (int i = 0; i < 2; ++i) {
            const int kk = bks + 8 * i;
            ushortx8 bv = {0, 0, 0, 0, 0, 0, 0, 0};
            if (bn_ok && (k0 + kk < K))
                bv = *(const ushortx8*)(WT + (size_t)(bn0 + brn) * K + k0 + kk);
            *(ushortx8*)&Bs[brn][SW(brn, kk)] = bv;
        }
        __syncthreads();
#pragma unroll
        for (int ks = 0; ks < 2; ++ks) {
            const int cc = ks * 32 + l4 * 8;
            bf16x8 af0 = *(const bf16x8*)&As[ra0][SW(ra0, cc)];
            bf16x8 af1 = *(const bf16x8*)&As[ra1][SW(ra1, cc)];
            bf16x8 bg0 = *(const bf16x8*)&Bs[rb0][SW(rb0, cc)];
            bf16x8 bg1 = *(const bf16x8*)&Bs[rb1][SW(rb1, cc)];
            acc[0][0] = __builtin_amdgcn_mfma_f32_16x16x32_bf16(af0, bg0, acc[0][0], 0, 0, 0);
            acc[0][1] = __builtin_amdgcn_mfma_f32_16x16x32_bf16(af0, bg1, acc[0][1], 0, 0, 0);
            acc[1][0] = __builtin_amdgcn_mfma_f32_16x16x32_bf16(af1, bg0, acc[1][0], 0, 0, 0);
            acc[1][1] = __builtin_amdgcn_mfma_f32_16x16x32_bf16(af1, bg1, acc[1][1], 0, 0, 0);
        }
        __syncthreads();
    }

#pragma unroll
    for (int fi = 0; fi < 2; ++fi)
#pragma unroll
        for (int fj = 0; fj < 2; ++fj) {
            const int ocol = bn0 + wc * 32 + fj * 16 + l15;
            if (ocol < Nc) {
#pragma unroll
                for (int p = 0; p < 4; ++p) {
                    const int orow = bm0 + wr * 32 + fi * 16 + l4 * 4 + p;
                    float v = acc[fi][fj][p];
                    if (post == 1) v = tanhf(v);
                    else if (post == 2) v = 1.0f / (1.0f + expf(-v));
                    if (outh)
                        outh[(size_t)orow * 320 + hoff + ocol] = f2bf(v);
                    else
                        outp[((size_t)orow * 1024 + ocol) * ostr + ooff] = f2bf(v);
                }
            }
        }
}

// ---------------- stage-1: 7 GEMMs in one launch ----------------
__global__ __launch_bounds__(256) void gemm_s1_kernel(
    const unsigned short* xr, const unsigned short* xk, const unsigned short* xv,
    const unsigned short* xw, const unsigned short* xa, const unsigned short* xg,
    const unsigned short* wtA, const unsigned short* wtB, const unsigned short* wtC,
    const unsigned short* wt_a1, const unsigned short* wt_v1,
    const unsigned short* wt_g1, const unsigned short* wt_w1,
    unsigned short* b_r, unsigned short* pk_bf, unsigned short* b_v,
    unsigned short* h_cat)
{
    const int nt = blockIdx.x;
    const int bm0 = blockIdx.y * GBM;
    const unsigned short* A; const unsigned short* WT;
    unsigned short* outp = nullptr; unsigned short* outh = nullptr;
    int Nc = 1024, nb = 0, ostr = 1, ooff = 0, hoff = 0, post = 0;
    if (nt < 16)      { A = xr; WT = wtC; outp = b_r; nb = nt; }
    else if (nt < 32) { A = xk; WT = wtA; outp = pk_bf; ostr = 4; ooff = 1; nb = nt - 16; }
    else if (nt < 48) { A = xv; WT = wtB; outp = b_v; nb = nt - 32; }
    else if (nt == 48){ A = xa; WT = wt_a1; outh = h_cat; hoff = 0;   Nc = 64; }
    else if (nt == 49){ A = xv; WT = wt_v1; outh = h_cat; hoff = 64;  Nc = 32; }
    else if (nt < 53) { A = xg; WT = wt_g1; outh = h_cat; hoff = 96;  Nc = 160; nb = nt - 50; post = 2; }
    else              { A = xw; WT = wt_w1; outh = h_cat; hoff = 256; Nc = 64; post = 1; }
    gemm_core(A, 1024, WT, 1024, Nc, nb * 64, bm0, outp, ostr, ooff, outh, hoff, post);
}

// ---------------- stage-2: 4 GEMMs in one launch (A = h_cat) ----------------
__global__ __launch_bounds__(256) void gemm_s2_kernel(
    const unsigned short* __restrict__ h_cat,
    const unsigned short* wt_a2, const unsigned short* wt_v2,
    const unsigned short* wt_g2, const unsigned short* wt_w2,
    unsigned short* pk_bf, unsigned short* b_g)
{
    const int g = blockIdx.x >> 4;
    const int nb = blockIdx.x & 15;
    const int bm0 = blockIdx.y * GBM;
    const unsigned short* WT;
    unsigned short* outp; int K, aoff, ostr, ooff;
    if      (g == 0) { WT = wt_a2; K = 64;  aoff = 0;   outp = pk_bf; ostr = 4; ooff = 2; }
    else if (g == 1) { WT = wt_v2; K = 32;  aoff = 64;  outp = pk_bf; ostr = 4; ooff = 3; }
    else if (g == 2) { WT = wt_g2; K = 160; aoff = 96;  outp = b_g;   ostr = 1; ooff = 0; }
    else             { WT = wt_w2; K = 64;  aoff = 256; outp = pk_bf; ostr = 4; ooff = 0; }
    gemm_core(h_cat + aoff, 320, WT, K, 1024, nb * 64, bm0, outp, ostr, ooff, nullptr, 0, 0);
}

// ---------------- final GEMM: out = y_bf @ W_o + residual (f32 out) ----------------
__global__ __launch_bounds__(256) void gemm_final_kernel(
    const unsigned short* __restrict__ Y, const unsigned short* __restrict__ WT,
    const float* __restrict__ addend, float* __restrict__ out)
{
    const int K = 1024;
    __shared__ unsigned short As[GBM][LDK];
    __shared__ unsigned short Bs[GBN][LDK];

    const int tid = threadIdx.x;
    const int lane = tid & 63;
    const int wid = tid >> 6;
    const int wr = wid >> 1, wc = wid & 1;
    const int l15 = lane & 15, l4 = lane >> 4;
    const int bm0 = blockIdx.y * GBM;
    const int bn0 = blockIdx.x * GBN;
    const int ar = tid >> 2;
    const int as = (tid & 3) << 4;
    const int row = bm0 + ar;
    const int brn = tid >> 2;
    const int bks = (tid & 3) << 4;

    const int ra0 = wr * 32 + l15, ra1 = wr * 32 + 16 + l15;
    const int rb0 = wc * 32 + l15, rb1 = wc * 32 + 16 + l15;

    f32x4 acc[2][2] = {};

    for (int k0 = 0; k0 < K; k0 += GBK) {
#pragma unroll
        for (int i = 0; i < 2; ++i) {
            const int kk = as + 8 * i;
            *(ushortx8*)&As[ar][SW(ar, kk)] =
                *(const ushortx8*)(Y + (size_t)row * 1024 + k0 + kk);
        }
#pragma unroll
        for (int i = 0; i < 2; ++i) {
            const int kk = bks + 8 * i;
            *(ushortx8*)&Bs[brn][SW(brn, kk)] =
                *(const ushortx8*)(WT + (size_t)(bn0 + brn) * K + k0 + kk);
        }
        __syncthreads();
#pragma unroll
        for (int ks = 0; ks < 2; ++ks) {
            const int cc = ks * 32 + l4 * 8;
            bf16x8 af0 = *(const bf16x8*)&As[ra0][SW(ra0, cc)];
            bf16x8 af1 = *(const bf16x8*)&As[ra1][SW(ra1, cc)];
            bf16x8 bg0 = *(const bf16x8*)&Bs[rb0][SW(rb0, cc)];
            bf16x8 bg1 = *(const bf16x8*)&Bs[rb1][SW(rb1, cc)];
            acc[0][0] = __builtin_amdgcn_mfma_f32_16x16x32_bf16(af0, bg0, acc[0][0], 0, 0, 0);
            acc[0][1] = __builtin_amdgcn_mfma_f32_16x16x32_bf16(af0, bg1, acc[0][1], 0, 0, 0);
            acc[1][0] = __builtin_amdgcn_mfma_f32_16x16x32_bf16(af1, bg0, acc[1][0], 0, 0, 0);
            acc[1][1] = __builtin_amdgcn_mfma_f32_16x16x32_bf16(af1, bg1, acc[1][1], 0, 0, 0);
        }
        __syncthreads();
    }

#pragma unroll
    for (int fi = 0; fi < 2; ++fi)
#pragma unroll
        for (int fj = 0; fj < 2; ++fj) {
            const int ocol = bn0 + wc * 32 + fj * 16 + l15;
#pragma unroll
            for (int p = 0; p < 4; ++p) {
                const int orow = bm0 + wr * 32 + fi * 16 + l4 * 4 + p;
                out[(size_t)orow * 1024 + ocol] =
                    acc[fi][fj][p] + addend[(size_t)orow * 1024 + ocol];
            }
        }
}

// ---------------- chunked-scan PREP (stage3 folded in, MFMA-ized) ----------------
// Per block: one (bh, chunk of 32 steps). 4 waves.
// Recurrence: S_t = S_{t-1}(diag(ew_t) + aa_t bb_t^T) + v_t ko_t^T.
// Outputs per chunk (layouts identical to the verified round-10 version):
//   Gt[t][n], LRt[n][k'], Vc[vi][n] f32, Wl[n], Oi[t][vi], plus b_v update & TB.
__global__ __launch_bounds__(256) void chunk_prep_kernel(
    const unsigned short* __restrict__ pk_bf,
    const unsigned short* __restrict__ b_r,
    unsigned short* __restrict__ b_v,
    const float* __restrict__ v_first,
    const float* w0, const float* a0, const float* v0,
    const float* k_k, const float* k_a, const float* r_k,
    float* __restrict__ TB,
    unsigned short* __restrict__ Gt, unsigned short* __restrict__ LRt,
    float* __restrict__ Vc, float* __restrict__ Wl,
    unsigned short* __restrict__ Oi)
{
    // ---- LDS arena (60800 B) with phase overlays ----
    __shared__ __align__(16) char smem[60800];
    unsigned short (*tB)[72]  = (unsigned short (*)[72])(smem + 0);
    unsigned short (*tK)[72]  = (unsigned short (*)[72])(smem + 4608);
    unsigned short (*tR)[72]  = (unsigned short (*)[72])(smem + 9216);
    unsigned short (*tBT)[40] = (unsigned short (*)[40])(smem + 13824);
    unsigned short (*VlT)[40] = (unsigned short (*)[40])(smem + 18944);
    unsigned short (*egT)[40] = (unsigned short (*)[40])(smem + 24064);
    float (*W32s)[66]         = (float (*)[66])(smem + 26624);
    float (*fg)[33]           = (float (*)[33])(smem + 35072);
    unsigned short (*tA)[72]  = (unsigned short (*)[72])(smem + 39296); // dead after F
    float (*cg)[33]           = (float (*)[33])(smem + 43904);          // dead after F
    unsigned short (*ZB)[40]  = (unsigned short (*)[40])(smem + 39296); // over tA
    unsigned short (*DhB)[40] = (unsigned short (*)[40])(smem + 44416); // over cg
    float (*dg)[33]           = (float (*)[33])(smem + 48128);          // dead after F2
    unsigned short (*fT)[40]  = (unsigned short (*)[40])(smem + 48128); // over dg
    float* EWZ                = (float*)(smem + 52352);                 // dead after F2
    unsigned short (*KtT)[40] = (unsigned short (*)[40])(smem + 52352); // over EWZ

    const int tid = threadIdx.x;
    const int lane = tid & 63;
    const int w = tid >> 6;
    const int l15 = lane & 15, l4 = lane >> 4;
    const int bhc = blockIdx.x;
    const int bh = bhc >> 5, ck = bhc & 31;
    const int b = bh >> 4, h = bh & 15;
    const int cglob = h * 64 + lane;

    // ---- Phase A: loads + stage3 elementwise + raw stores ----
    const float kkc = k_k[cglob], kac = k_a[cglob];
    const float a0c = a0[cglob], v0c = v0[cglob];
    const float w0c = w0[cglob], rkc = r_k[cglob];
#pragma unroll
    for (int q = 0; q < 8; ++q) {
        const int tq = w * 8 + q;
        const int row = b * 1024 + ck * 32 + tq;
        const size_t gi = (size_t)row * 1024 + cglob;
        const ushortx4 pk = *(const ushortx4*)(pk_bf + gi * 4);
        const float kl = bf2f(pk.y);
        const float kkv = kl * kkc;
        const float ss = wred64(kkv * kkv);
        const float kkn = kkv / fmaxf(sqrtf(ss), 1e-12f);
        const float a = 1.0f / (1.0f + expf(-(a0c + bf2f(pk.z))));
        const float u = w0c + bf2f(pk.x);
        const float ew = expf(-expf(-log1pf(expf(-u)) - 0.5f));
        const float sv = 1.0f / (1.0f + expf(-(v0c + bf2f(pk.w))));
        const float vl = bf2f(b_v[gi]);
        const float v = fmaf(v_first[gi] - vl, sv, vl);
        const float ko = kl * (1.0f + (a - 1.0f) * kac);
        const unsigned short rbf = b_r[gi];
        const float r1f = bf2f(rbf);
        const unsigned short vbf = f2bf(v);
        b_v[gi] = vbf;

        const float t3 = wred64(r1f * ko * rkc);
        if (lane == 0) TB[bh * 1024 + ck * 32 + tq] = t3;

        EWZ[tq * 64 + lane] = ew;
        tA[tq][lane] = f2bf(-kkn);
        tB[tq][lane] = f2bf(kkn * a);
        tK[tq][lane] = f2bf(ko);
        tR[tq][lane] = rbf;
        VlT[lane][tq] = vbf;
    }
    __syncthreads();

    // ---- Phase B: decay cumprods (wave 0) ----
    if (w == 0) {
        float run = 1.0f;
        for (int t = 0; t < 32; ++t) {
            run *= EWZ[t * 64 + lane];
            W32s[t][lane] = run;
        }
    }
    __syncthreads();

    // ---- Phase C: tildes in place + tBT ----
#pragma unroll
    for (int q = 0; q < 8; ++q) {
        const int tq = w * 8 + q;
        const float Wt = W32s[tq][lane];
        const float Wm1 = tq ? W32s[tq - 1][lane] : 1.0f;
        const float iw = 1.0f / Wt;
        tA[tq][lane] = f2bf(bf2f(tA[tq][lane]) * Wm1);
        const unsigned short tb = f2bf(bf2f(tB[tq][lane]) * iw);
        tB[tq][lane] = tb;
        tBT[lane][tq] = tb;
        tK[tq][lane] = f2bf(bf2f(tK[tq][lane]) * iw);
        tR[tq][lane] = f2bf(bf2f(tR[tq][lane]) * Wt);
    }
    __syncthreads();

    // ---- Phase D: four 32x32 Grams via MFMA (one per wave) ----
    {
        const unsigned short (*Am)[72] = (w == 0 || w == 2) ? tB : tK;
        const unsigned short (*Bm)[72] = (w < 2) ? tA : tR;
        f32x4 gacc[2][2] = {};
#pragma unroll
        for (int kh = 0; kh < 2; ++kh) {
            const int cc = kh * 32 + l4 * 8;
            bf16x8 ax0 = *(const bf16x8*)&Am[l15][cc];
            bf16x8 ax1 = *(const bf16x8*)&Am[16 + l15][cc];
            bf16x8 bx0 = *(const bf16x8*)&Bm[l15][cc];
            bf16x8 bx1 = *(const bf16x8*)&Bm[16 + l15][cc];
            gacc[0][0] = __builtin_amdgcn_mfma_f32_16x16x32_bf16(ax0, bx0, gacc[0][0], 0, 0, 0);
            gacc[0][1] = __builtin_amdgcn_mfma_f32_16x16x32_bf16(ax0, bx1, gacc[0][1], 0, 0, 0);
            gacc[1][0] = __builtin_amdgcn_mfma_f32_16x16x32_bf16(ax1, bx0, gacc[1][0], 0, 0, 0);
            gacc[1][1] = __builtin_amdgcn_mfma_f32_16x16x32_bf16(ax1, bx1, gacc[1][1], 0, 0, 0);
        }
#pragma unroll
        for (int mt = 0; mt < 2; ++mt)
#pragma unroll
            for (int nt = 0; nt < 2; ++nt) {
                const int col = nt * 16 + l15;
                if (w == 2) {   // eg[i][t] -> egT[t][i]
                    ushortx4 st;
#pragma unroll
                    for (int p = 0; p < 4; ++p) st[p] = f2bf(gacc[mt][nt][p]);
                    *(ushortx4*)&egT[col][mt * 16 + l4 * 4] = st;
                } else {
#pragma unroll
                    for (int p = 0; p < 4; ++p) {
                        const int rw = mt * 16 + l4 * 4 + p;
                        if (w == 0) cg[rw][col] = gacc[mt][nt][p];
                        else if (w == 1) dg[rw][col] = gacc[mt][nt][p];
                        else fg[rw][col] = gacc[mt][nt][p];
                    }
                }
            }
    }
    __syncthreads();

    // ---- Phase E: zero invalid triangles ----
#pragma unroll
    for (int p = 0; p < 4; ++p) {
        const int idx = tid * 4 + p;
        const int r_ = idx >> 5, c_ = idx & 31;
        if (r_ >= c_) cg[r_][c_] = 0.0f;     // keep j<i
        if (c_ <= r_) dg[r_][c_] = 0.0f;     // keep j>i
        if (r_ > c_) fg[r_][c_] = 0.0f;      // keep i<=t
        if (c_ > r_) egT[r_][c_] = 0;        // egT[t][i]: keep i<=t
    }
    __syncthreads();

    // ---- Phase F: triangular recurrences (serial, conflict-free) ----
    if (w == 0) {
        for (int i = 0; i < 32; ++i) {       // Z[n][i]
            float val = bf2f(tA[i][lane]);
            for (int j = 0; j < i; ++j) val += cg[j][i] * EWZ[lane * 33 + j];
            EWZ[lane * 33 + i] = val;
        }
    } else if (w == 1 && lane < 32) {
        for (int t = 0; t < 32; ++t) {       // Dhat in place over dg
            float val = dg[lane][t];
            for (int j = 0; j < t; ++j) val += cg[j][t] * dg[lane][j];
            dg[lane][t] = val;
        }
    }
    __syncthreads();

    // ---- Phase F2: bf16 copies (DhB over cg, ZB over tA) ----
#pragma unroll
    for (int p = 0; p < 4; ++p) {
        const int idx = tid * 4 + p;
        DhB[idx >> 5][idx & 31] = f2bf(dg[idx >> 5][idx & 31]);
    }
#pragma unroll
    for (int p = 0; p < 8; ++p) {
        const int idx = tid * 8 + p;
        ZB[idx >> 5][idx & 31] = f2bf(EWZ[(idx >> 5) * 33 + (idx & 31)]);
    }
    __syncthreads();

    const size_t cb2048 = (size_t)bhc * 2048;
    const size_t cb4096 = (size_t)bhc * 4096;

    // ---- Phase G-a ----
    if (w == 0) {
        // f[i][t] = fg + Dhat@eg -> fT[t][i]
#pragma unroll
        for (int mt = 0; mt < 2; ++mt)
#pragma unroll
            for (int nt = 0; nt < 2; ++nt) {
                f32x4 cacc;
#pragma unroll
                for (int p = 0; p < 4; ++p) cacc[p] = fg[mt * 16 + l4 * 4 + p][nt * 16 + l15];
                bf16x8 ax = *(const bf16x8*)&DhB[mt * 16 + l15][l4 * 8];
                bf16x8 bx = *(const bf16x8*)&egT[nt * 16 + l15][l4 * 8];
                cacc = __builtin_amdgcn_mfma_f32_16x16x32_bf16(ax, bx, cacc, 0, 0, 0);
                ushortx4 st;
#pragma unroll
                for (int p = 0; p < 4; ++p) st[p] = f2bf(cacc[p]);
                *(ushortx4*)&fT[nt * 16 + l15][mt * 16 + l4 * 4] = st;
            }
    } else if (w == 1) {
        // Ktilde[i][n] = (Khat + Dhat@Btilde)*W31[n] -> KtT[n][i]
#pragma unroll
        for (int mt = 0; mt < 2; ++mt)
#pragma unroll
            for (int nt = 0; nt < 4; ++nt) {
                bf16x8 ax = *(const bf16x8*)&DhB[mt * 16 + l15][l4 * 8];
                bf16x8 bx = *(const bf16x8*)&tBT[nt * 16 + l15][l4 * 8];
                f32x4 cacc = {};
                cacc = __builtin_amdgcn_mfma_f32_16x16x32_bf16(ax, bx, cacc, 0, 0, 0);
                const int col = nt * 16 + l15;
                const float w31c = W32s[31][col];
                ushortx4 st;
#pragma unroll
                for (int p = 0; p < 4; ++p) {
                    const int rw = mt * 16 + l4 * 4 + p;
                    st[p] = f2bf((cacc[p] + bf2f(tK[rw][col])) * w31c);
                }
                *(ushortx4*)&KtT[col][mt * 16 + l4 * 4] = st;
            }
    } else if (w == 2) {
        // LRt[n][k'] = W31[n] * sum_i tB[i][n] Z[k'][i]
#pragma unroll
        for (int mt = 0; mt < 4; ++mt)
#pragma unroll
            for (int nt = 0; nt < 4; ++nt) {
                bf16x8 ax = *(const bf16x8*)&tBT[mt * 16 + l15][l4 * 8];
                bf16x8 bx = *(const bf16x8*)&ZB[nt * 16 + l15][l4 * 8];
                f32x4 cacc = {};
                cacc = __builtin_amdgcn_mfma_f32_16x16x32_bf16(ax, bx, cacc, 0, 0, 0);
                const int kcol = nt * 16 + l15;
#pragma unroll
                for (int p = 0; p < 4; ++p) {
                    const int n_ = mt * 16 + l4 * 4 + p;
                    LRt[cb4096 + n_ * 64 + kcol] = f2bf(cacc[p] * W32s[31][n_]);
                }
            }
    } else {
        // Gt[t][n] = tR + sum_i eg[i][t] Z[n][i]
#pragma unroll
        for (int mt = 0; mt < 2; ++mt)
#pragma unroll
            for (int nt = 0; nt < 4; ++nt) {
                bf16x8 ax = *(const bf16x8*)&egT[mt * 16 + l15][l4 * 8];
                bf16x8 bx = *(const bf16x8*)&ZB[nt * 16 + l15][l4 * 8];
                f32x4 cacc = {};
                cacc = __builtin_amdgcn_mfma_f32_16x16x32_bf16(ax, bx, cacc, 0, 0, 0);
                const int ncol = nt * 16 + l15;
#pragma unroll
                for (int p = 0; p < 4; ++p) {
                    const int t_ = mt * 16 + l4 * 4 + p;
                    Gt[cb2048 + t_ * 64 + ncol] = f2bf(cacc[p] + bf2f(tR[t_][ncol]));
                }
            }
    }
    __syncthreads();

    // ---- Phase G-b ----
    if (w < 2) {
        // Oi[t][vi] = sum_i f[i][t] Vl[i][vi]; wave w takes vi-tiles {2w, 2w+1}
#pragma unroll
        for (int mt = 0; mt < 2; ++mt)
#pragma unroll
            for (int ntl = 0; ntl < 2; ++ntl) {
                const int nt = w * 2 + ntl;
                bf16x8 ax = *(const bf16x8*)&fT[mt * 16 + l15][l4 * 8];
                bf16x8 bx = *(const bf16x8*)&VlT[nt * 16 + l15][l4 * 8];
                f32x4 cacc = {};
                cacc = __builtin_amdgcn_mfma_f32_16x16x32_bf16(ax, bx, cacc, 0, 0, 0);
                const int vcol = nt * 16 + l15;
#pragma unroll
                for (int p = 0; p < 4; ++p) {
                    const int t_ = mt * 16 + l4 * 4 + p;
                    Oi[cb2048 + t_ * 64 + vcol] = f2bf(cacc[p]);
                }
            }
    } else {
        // Vc[vi][n] = sum_i Vl[i][vi] Ktilde[i][n]; wave takes vi-tiles {2(w-2), +1}
#pragma unroll
        for (int mtl = 0; mtl < 2; ++mtl)
#pragma unroll
            for (int nt = 0; nt < 4; ++nt) {
                const int mt = (w - 2) * 2 + mtl;
                bf16x8 ax = *(const bf16x8*)&VlT[mt * 16 + l15][l4 * 8];
                bf16x8 bx = *(const bf16x8*)&KtT[nt * 16 + l15][l4 * 8];
                f32x4 cacc = {};
                cacc = __builtin_amdgcn_mfma_f32_16x16x32_bf16(ax, bx, cacc, 0, 0, 0);
                const int ncol = nt * 16 + l15;
#pragma unroll
                for (int p = 0; p < 4; ++p) {
                    const int vi_ = mt * 16 + l4 * 4 + p;
                    Vc[cb4096 + (size_t)vi_ * 64 + ncol] = cacc[p];
                }
            }
    }
    if (tid < 64) Wl[(size_t)bhc * 64 + tid] = W32s[31][tid];
}

// ---------------- chunked-scan SEQ: 32 blocks (one per bh), MFMA ----------------
__global__ __launch_bounds__(256) void chunk_seq_kernel(
    const unsigned short* __restrict__ Gt, const unsigned short* __restrict__ LRt,
    const float* __restrict__ Vc, const float* __restrict__ Wl,
    const unsigned short* __restrict__ Oi, unsigned short* __restrict__ o)
{
    __shared__ unsigned short Sst[4][16][80];
    const int tid = threadIdx.x, lane = tid & 63, w = tid >> 6;
    const int bh = blockIdx.x;
    const int b = bh >> 4, h = bh & 15;
    const int l15 = lane & 15, l4 = lane >> 4;

    f32x4 sC[4] = {};

    for (int c = 0; c < 32; ++c) {
        const size_t cb = (size_t)(bh * 32 + c);
#pragma unroll
        for (int nt = 0; nt < 4; ++nt)
#pragma unroll
            for (int p = 0; p < 4; ++p)
                Sst[w][l4 * 4 + p][nt * 16 + l15] = f2bf(sC[nt][p]);
        __syncthreads();

        bf16x8 a0 = *(const bf16x8*)&Sst[w][l15][l4 * 8];
        bf16x8 a1 = *(const bf16x8*)&Sst[w][l15][32 + l4 * 8];
        __syncthreads();

        const unsigned short* gt = Gt + cb * 2048;
        const unsigned short* lr = LRt + cb * 4096;

        f32x4 oacc[2] = {};
#pragma unroll
        for (int tt = 0; tt < 2; ++tt) {
            bf16x8 g0 = *(const bf16x8*)&gt[(tt * 16 + l15) * 64 + l4 * 8];
            bf16x8 g1 = *(const bf16x8*)&gt[(tt * 16 + l15) * 64 + 32 + l4 * 8];
            oacc[tt] = __builtin_amdgcn_mfma_f32_16x16x32_bf16(a0, g0, oacc[tt], 0, 0, 0);
            oacc[tt] = __builtin_amdgcn_mfma_f32_16x16x32_bf16(a1, g1, oacc[tt], 0, 0, 0);
        }
        f32x4 lac[4] = {};
#pragma unroll
        for (int nt = 0; nt < 4; ++nt) {
            bf16x8 r0 = *(const bf16x8*)&lr[(nt * 16 + l15) * 64 + l4 * 8];
            bf16x8 r1 = *(const bf16x8*)&lr[(nt * 16 + l15) * 64 + 32 + l4 * 8];
            lac[nt] = __builtin_amdgcn_mfma_f32_16x16x32_bf16(a0, r0, lac[nt], 0, 0, 0);
            lac[nt] = __builtin_amdgcn_mfma_f32_16x16x32_bf16(a1, r1, lac[nt], 0, 0, 0);
        }

#pragma unroll
        for (int nt = 0; nt < 4; ++nt) {
            const float wlv = Wl[cb * 64 + nt * 16 + l15];
#pragma unroll
            for (int p = 0; p < 4; ++p) {
                const int vi = w * 16 + l4 * 4 + p;
                const float vcv = Vc[cb * 4096 + (size_t)vi * 64 + nt * 16 + l15];
                sC[nt][p] = sC[nt][p] * wlv + lac[nt][p] + vcv;
            }
        }

#pragma unroll
        for (int tt = 0; tt < 2; ++tt) {
            const int trow = b * 1024 + c * 32 + tt * 16 + l15;
            const int vib = w * 16 + l4 * 4;
            ushortx4 oi = *(const ushortx4*)(Oi + cb * 2048 + (tt * 16 + l15) * 64 + vib);
            ushortx4 ov;
            ov.x = f2bf(oacc[tt][0] + bf2f(oi.x));
            ov.y = f2bf(oacc[tt][1] + bf2f(oi.y));
            ov.z = f2bf(oacc[tt][2] + bf2f(oi.z));
            ov.w = f2bf(oacc[tt][3] + bf2f(oi.w));
            *(ushortx4*)(o + (size_t)trow * 1024 + h * 64 + vib) = ov;
        }
    }
}

// ---------------- groupnorm + bonus + gate (bf16 in, bf16 y out) ----------------
__global__ __launch_bounds__(256) void post_kernel(
    const unsigned short* o, const unsigned short* v, const unsigned short* g,
    const float* __restrict__ TB,
    const float* ln_w, const float* ln_b,
    unsigned short* y)
{
    const int gw = (blockIdx.x * blockDim.x + threadIdx.x) >> 6;
    const int lane = threadIdx.x & 63;
    const int row = gw >> 4;
    const int h = gw & 15;
    const int c = h * N_DIM + lane;
    const size_t idx = (size_t)row * C_DIM + c;
    const int b = row >> 10;
    const int t = row & 1023;

    const float oo = bf2f(o[idx]);
    float s1 = oo, s2 = oo * oo;
#pragma unroll
    for (int m = 32; m; m >>= 1) {
        s1 += __shfl_xor(s1, m);
        s2 += __shfl_xor(s2, m);
    }
    const float mu = s1 * (1.0f / 64.0f);
    const float var = s2 * (1.0f / 64.0f) - mu * mu;
    float yv = (oo - mu) * rsqrtf(var + 0.00064f);
    yv = yv * ln_w[c] + ln_b[c];

    yv += TB[(b * 16 + h) * 1024 + t] * bf2f(v[idx]);
    y[idx] = f2bf(yv * bf2f(g[idx]));
}

extern "C" void kernel_launch(void* const* d_in, const int* in_sizes, int n_in,
                              void* d_out, int out_size, void* d_ws, size_t ws_size,
                              hipStream_t stream) {
    (void)in_sizes; (void)n_in; (void)out_size; (void)ws_size;

    const float* residual = (const float*)d_in[0];
    const float* x        = (const float*)d_in[1];
    const float* v_first  = (const float*)d_in[2];
    const float* mr = (const float*)d_in[6];
    const float* mw = (const float*)d_in[7];
    const float* mk = (const float*)d_in[8];
    const float* mv = (const float*)d_in[9];
    const float* ma = (const float*)d_in[10];
    const float* mg = (const float*)d_in[11];
    const float* w0 = (const float*)d_in[12];
    const float* w1 = (const float*)d_in[13];
    const float* w2 = (const float*)d_in[14];
    const float* a0 = (const float*)d_in[15];
    const float* a1 = (const float*)d_in[16];
    const float* a2 = (const float*)d_in[17];
    const float* v0 = (const float*)d_in[18];
    const float* v1 = (const float*)d_in[19];
    const float* v2 = (const float*)d_in[20];
    const float* g1 = (const float*)d_in[21];
    const float* g2 = (const float*)d_in[22];
    const float* k_k = (const float*)d_in[23];
    const float* k_a = (const float*)d_in[24];
    const float* r_k = (const float*)d_in[25];
    const float* W_r = (const float*)d_in[26];
    const float* W_k = (const float*)d_in[27];
    const float* W_v = (const float*)d_in[28];
    const float* W_o = (const float*)d_in[29];
    const float* ln_w = (const float*)d_in[30];
    const float* ln_b = (const float*)d_in[31];

    float* out = (float*)d_out;
    char* wsb = (char*)d_ws;

    // ---- workspace layout (bytes); max end 69,730,304 (proven safe) ----
    unsigned short* xr = (unsigned short*)(wsb + 0);
    unsigned short* xk = (unsigned short*)(wsb + 4194304);
    unsigned short* xv = (unsigned short*)(wsb + 8388608);
    unsigned short* xw = (unsigned short*)(wsb + 12582912);
    unsigned short* xa = (unsigned short*)(wsb + 16777216);
    unsigned short* xg = (unsigned short*)(wsb + 20971520);     // ends 25,165,824
    float* Vc          = (float*)(wsb + 0);                     // over xr..xv (post-s1)
    unsigned short* Gt = (unsigned short*)(wsb + 16777216);     // over xa
    unsigned short* Oi = (unsigned short*)(wsb + 20971520);     // over xg
    unsigned short* pk_bf = (unsigned short*)(wsb + 25165824);  // 16 MiB (dead after prep)
    unsigned short* wtD = (unsigned short*)(wsb + 25165824);    // 2 MiB (after prep)
    unsigned short* y_bf = (unsigned short*)(wsb + 27262976);   // 4 MiB
    unsigned short* b_r = (unsigned short*)(wsb + 41943040);
    unsigned short* b_v = (unsigned short*)(wsb + 46137344);
    unsigned short* b_o = (unsigned short*)(wsb + 50331648);
    unsigned short* b_g = (unsigned short*)(wsb + 54525952);
    unsigned short* h_cat = (unsigned short*)(wsb + 58720256);
    unsigned short* wt_a1 = (unsigned short*)(wsb + 60293120);
    unsigned short* wt_v1 = (unsigned short*)(wsb + 60424192);
    unsigned short* wt_g1 = (unsigned short*)(wsb + 60489728);
    unsigned short* wt_a2 = (unsigned short*)(wsb + 60817408);
    unsigned short* wt_v2 = (unsigned short*)(wsb + 60948480);
    unsigned short* wt_g2 = (unsigned short*)(wsb + 61014016);
    unsigned short* wt_w1 = (unsigned short*)(wsb + 61341696);
    unsigned short* wt_w2 = (unsigned short*)(wsb + 61472768);
    unsigned short* wtA = (unsigned short*)(wsb + 61603840);
    unsigned short* wtB = (unsigned short*)(wsb + 63700992);
    unsigned short* wtC = (unsigned short*)(wsb + 65798144);    // ends 67,895,296
    unsigned short* LRt = (unsigned short*)(wsb + 60030976);    // 8 MiB over dead wts
    float* Wl = (float*)(wsb + 68419584);
    float* TB = (float*)(wsb + 68681728);

    const dim3 blk(256);
    const dim3 tblk(32, 8);

    // 1) premix
    premix_kernel<<<dim3(1024), blk, 0, stream>>>(
        x, mr, mk, mv, mw, ma, mg, xr, xk, xv, xw, xa, xg);

    // 2) transpose W_k, W_v, W_r + all small weights
    trans_all_kernel<<<dim3(3712), tblk, 0, stream>>>(
        W_k, W_v, W_r, w1, a1, v1, g1, a2, v2, g2, w2,
        wtA, wtB, wtC, wt_w1, wt_a1, wt_v1, wt_g1, wt_a2, wt_v2, wt_g2, wt_w2);

    // 3) stage-1: r, k, v, a1, v1, g1, w1
    gemm_s1_kernel<<<dim3(54, 32), blk, 0, stream>>>(
        xr, xk, xv, xw, xa, xg, wtA, wtB, wtC,
        wt_a1, wt_v1, wt_g1, wt_w1, b_r, pk_bf, b_v, h_cat);

    // 4) stage-2: a2, v2, g2, w2
    gemm_s2_kernel<<<dim3(64, 32), blk, 0, stream>>>(
        h_cat, wt_a2, wt_v2, wt_g2, wt_w2, pk_bf, b_g);

    // 5) chunk prep (stage3 folded in, MFMA-ized WY transform)
    chunk_prep_kernel<<<dim3(1024), blk, 0, stream>>>(
        pk_bf, b_r, b_v, v_first, w0, a0, v0, k_k, k_a, r_k,
        TB, Gt, LRt, Vc, Wl, Oi);

    // 6) W_o transpose (over dead pk_bf head)
    wtrans_kernel<<<dim3(32, 32), tblk, 0, stream>>>(W_o, wtD);

    // 7) sequential chunk scan (MFMA)
    chunk_seq_kernel<<<dim3(32), blk, 0, stream>>>(Gt, LRt, Vc, Wl, Oi, b_o);

    // 8) groupnorm + bonus + gate
    post_kernel<<<dim3(8192), blk, 0, stream>>>(
        b_o, b_v, b_g, TB, ln_w, ln_b, y_bf);

    // 9) output projection + residual
    gemm_final_kernel<<<dim3(16, 32), blk, 0, stream>>>(y_bf, wtD, residual, out);
}

// Round 12
// 165.170 us; speedup vs baseline: 1.5851x; 1.2613x over previous
//
#include <hip/hip_runtime.h>
#include <math.h>

// Problem constants
#define B_DIM 2
#define T_SEQ 1024
#define C_DIM 1024
#define H_DIM 16
#define N_DIM 64
#define M_ROWS (B_DIM * T_SEQ)   // 2048

// MFMA GEMM tiling
#define GBM 64
#define GBN 64
#define GBK 64
#define LDK 88

// LDS column swizzle for GEMM tiles
#define SW(r, c) ((c) ^ (((((r) >> 3) & 3)) << 3))

typedef __attribute__((ext_vector_type(8))) short bf16x8;
typedef __attribute__((ext_vector_type(4))) float f32x4;
typedef unsigned short ushortx4 __attribute__((ext_vector_type(4)));
typedef unsigned short ushortx8 __attribute__((ext_vector_type(8)));

__device__ __forceinline__ unsigned short f2bf(float f) {
    unsigned int u = __float_as_uint(f);
    u = (u + 0x7FFFu + ((u >> 16) & 1u)) >> 16;   // RNE
    return (unsigned short)u;
}
__device__ __forceinline__ float bf2f(unsigned short h) {
    return __uint_as_float(((unsigned int)h) << 16);
}

__device__ __forceinline__ float wred64(float v) {
#pragma unroll
    for (int m = 32; m; m >>= 1) v += __shfl_xor(v, m);
    return v;
}

// ---------------- premix: all six token-shift mixes, fp32 -> bf16 ----------------
__global__ __launch_bounds__(256) void premix_kernel(
    const float* __restrict__ x,
    const float* mr, const float* mk, const float* mv,
    const float* mw, const float* ma, const float* mg,
    unsigned short* xr, unsigned short* xk, unsigned short* xv,
    unsigned short* xw, unsigned short* xa, unsigned short* xg)
{
    const int g = blockIdx.x * 256 + threadIdx.x;
    const size_t base = (size_t)g * 8;
    const int row = (int)(base >> 10);
    const int col = (int)(base & 1023);
    const int t_in = row & (T_SEQ - 1);

    const float* xp = x + (size_t)row * C_DIM + col;
    float4 a0 = *(const float4*)xp;
    float4 a1 = *(const float4*)(xp + 4);
    float4 p0 = make_float4(0.f, 0.f, 0.f, 0.f), p1 = p0;
    if (t_in > 0) {
        p0 = *(const float4*)(xp - C_DIM);
        p1 = *(const float4*)(xp - C_DIM + 4);
    }
    const float d0x = p0.x - a0.x, d0y = p0.y - a0.y, d0z = p0.z - a0.z, d0w = p0.w - a0.w;
    const float d1x = p1.x - a1.x, d1y = p1.y - a1.y, d1z = p1.z - a1.z, d1w = p1.w - a1.w;

    const float* ms[6] = {mr, mk, mv, mw, ma, mg};
    unsigned short* outs[6] = {xr, xk, xv, xw, xa, xg};
#pragma unroll
    for (int i = 0; i < 6; ++i) {
        const float4 m0 = *(const float4*)(ms[i] + col);
        const float4 m1 = *(const float4*)(ms[i] + col + 4);
        ushortx8 o;
        o[0] = f2bf(fmaf(d0x, m0.x, a0.x));
        o[1] = f2bf(fmaf(d0y, m0.y, a0.y));
        o[2] = f2bf(fmaf(d0z, m0.z, a0.z));
        o[3] = f2bf(fmaf(d0w, m0.w, a0.w));
        o[4] = f2bf(fmaf(d1x, m1.x, a1.x));
        o[5] = f2bf(fmaf(d1y, m1.y, a1.y));
        o[6] = f2bf(fmaf(d1z, m1.z, a1.z));
        o[7] = f2bf(fmaf(d1w, m1.w, a1.w));
        *(ushortx8*)(outs[i] + base) = o;
    }
}

// ---------------- single weight transpose (W_o, 1024x1024) ----------------
__global__ __launch_bounds__(256) void wtrans_kernel(
    const float* __restrict__ W, unsigned short* __restrict__ WT)
{
    __shared__ float tile[32][33];
    const int tx = threadIdx.x, ty = threadIdx.y;
    const int n0 = blockIdx.x * 32, k0 = blockIdx.y * 32;
#pragma unroll
    for (int i = 0; i < 4; ++i)
        tile[ty + i * 8][tx] = W[(size_t)(k0 + ty + i * 8) * 1024 + n0 + tx];
    __syncthreads();
#pragma unroll
    for (int i = 0; i < 4; ++i)
        WT[(size_t)(n0 + ty + i * 8) * 1024 + k0 + tx] = f2bf(tile[tx][ty + i * 8]);
}

// ---------------- batched transpose+convert: W_k, W_v, W_r + 8 small ----------------
__global__ __launch_bounds__(256) void trans_all_kernel(
    const float* Wk, const float* Wv, const float* Wr,
    const float* w1p, const float* a1p, const float* v1p, const float* g1p,
    const float* a2p, const float* v2p, const float* g2p, const float* w2p,
    unsigned short* wtA, unsigned short* wtB, unsigned short* wtC,
    unsigned short* wt_w1, unsigned short* wt_a1, unsigned short* wt_v1,
    unsigned short* wt_g1, unsigned short* wt_a2, unsigned short* wt_v2,
    unsigned short* wt_g2, unsigned short* wt_w2)
{
    __shared__ float tile[32][33];
    const int bid = blockIdx.x;
    const float* W; unsigned short* WT; int K, N, t0;
    if      (bid < 1024) { W = Wk;  WT = wtA;   K = 1024; N = 1024; t0 = 0;    }
    else if (bid < 2048) { W = Wv;  WT = wtB;   K = 1024; N = 1024; t0 = 1024; }
    else if (bid < 3072) { W = Wr;  WT = wtC;   K = 1024; N = 1024; t0 = 2048; }
    else if (bid < 3136) { W = w1p; WT = wt_w1; K = 1024; N = 64;   t0 = 3072; }
    else if (bid < 3200) { W = a1p; WT = wt_a1; K = 1024; N = 64;   t0 = 3136; }
    else if (bid < 3232) { W = v1p; WT = wt_v1; K = 1024; N = 32;   t0 = 3200; }
    else if (bid < 3392) { W = g1p; WT = wt_g1; K = 1024; N = 160;  t0 = 3232; }
    else if (bid < 3456) { W = a2p; WT = wt_a2; K = 64;   N = 1024; t0 = 3392; }
    else if (bid < 3488) { W = v2p; WT = wt_v2; K = 32;   N = 1024; t0 = 3456; }
    else if (bid < 3648) { W = g2p; WT = wt_g2; K = 160;  N = 1024; t0 = 3488; }
    else                 { W = w2p; WT = wt_w2; K = 64;   N = 1024; t0 = 3648; }
    const int lt = bid - t0;
    const int ntx = N >> 5;
    const int n0 = (lt % ntx) * 32;
    const int k0 = (lt / ntx) * 32;
    const int tx = threadIdx.x, ty = threadIdx.y;
#pragma unroll
    for (int i = 0; i < 4; ++i)
        tile[ty + i * 8][tx] = W[(size_t)(k0 + ty + i * 8) * N + n0 + tx];
    __syncthreads();
#pragma unroll
    for (int i = 0; i < 4; ++i)
        WT[(size_t)(n0 + ty + i * 8) * K + k0 + tx] = f2bf(tile[tx][ty + i * 8]);
}

// ---------------- generic MFMA GEMM core (bf16 A, bf16 B^T, LDS swizzled) ----------
__device__ __forceinline__ void gemm_core(
    const unsigned short* __restrict__ Aarr, int arow_stride,
    const unsigned short* __restrict__ WT, int K, int Nc, int bn0, int bm0,
    unsigned short* outp, int ostr, int ooff,
    unsigned short* outh, int hoff, int post)
{
    __shared__ unsigned short As[GBM][LDK];
    __shared__ unsigned short Bs[GBN][LDK];

    const int tid = threadIdx.x;
    const int lane = tid & 63;
    const int wid = tid >> 6;
    const int wr = wid >> 1, wc = wid & 1;
    const int l15 = lane & 15, l4 = lane >> 4;

    const int ar = tid >> 2;
    const int as = (tid & 3) << 4;
    const int row = bm0 + ar;
    const int brn = tid >> 2;
    const int bks = (tid & 3) << 4;
    const bool bn_ok = (bn0 + brn) < Nc;

    const int ra0 = wr * 32 + l15, ra1 = wr * 32 + 16 + l15;
    const int rb0 = wc * 32 + l15, rb1 = wc * 32 + 16 + l15;

    f32x4 acc[2][2] = {};

    for (int k0 = 0; k0 < K; k0 += GBK) {
#pragma unroll
        for (int i = 0; i < 2; ++i) {
            const int kk = as + 8 * i;
            ushortx8 av = {0, 0, 0, 0, 0, 0, 0, 0};
            if (k0 + kk < K)
                av = *(const ushortx8*)(Aarr + (size_t)row * arow_stride + k0 + kk);
            *(ushortx8*)&As[ar][SW(ar, kk)] = av;
        }
#pragma unroll
        for (int i = 0; i < 2; ++i) {
            const int kk = bks + 8 * i;
            ushortx8 bv = {0, 0, 0, 0, 0, 0, 0, 0};
            if (bn_ok && (k0 + kk < K))
                bv = *(const ushortx8*)(WT + (size_t)(bn0 + brn) * K + k0 + kk);
            *(ushortx8*)&Bs[brn][SW(brn, kk)] = bv;
        }
        __syncthreads();
#pragma unroll
        for (int ks = 0; ks < 2; ++ks) {
            const int cc = ks * 32 + l4 * 8;
            bf16x8 af0 = *(const bf16x8*)&As[ra0][SW(ra0, cc)];
            bf16x8 af1 = *(const bf16x8*)&As[ra1][SW(ra1, cc)];
            bf16x8 bg0 = *(const bf16x8*)&Bs[rb0][SW(rb0, cc)];
            bf16x8 bg1 = *(const bf16x8*)&Bs[rb1][SW(rb1, cc)];
            acc[0][0] = __builtin_amdgcn_mfma_f32_16x16x32_bf16(af0, bg0, acc[0][0], 0, 0, 0);
            acc[0][1] = __builtin_amdgcn_mfma_f32_16x16x32_bf16(af0, bg1, acc[0][1], 0, 0, 0);
            acc[1][0] = __builtin_amdgcn_mfma_f32_16x16x32_bf16(af1, bg0, acc[1][0], 0, 0, 0);
            acc[1][1] = __builtin_amdgcn_mfma_f32_16x16x32_bf16(af1, bg1, acc[1][1], 0, 0, 0);
        }
        __syncthreads();
    }

#pragma unroll
    for (int fi = 0; fi < 2; ++fi)
#pragma unroll
        for (int fj = 0; fj < 2; ++fj) {
            const int ocol = bn0 + wc * 32 + fj * 16 + l15;
            if (ocol < Nc) {
#pragma unroll
                for (int p = 0; p < 4; ++p) {
                    const int orow = bm0 + wr * 32 + fi * 16 + l4 * 4 + p;
                    float v = acc[fi][fj][p];
                    if (post == 1) v = tanhf(v);
                    else if (post == 2) v = 1.0f / (1.0f + expf(-v));
                    if (outh)
                        outh[(size_t)orow * 320 + hoff + ocol] = f2bf(v);
                    else
                        outp[((size_t)orow * 1024 + ocol) * ostr + ooff] = f2bf(v);
                }
            }
        }
}

// ---------------- stage-1: 7 GEMMs in one launch ----------------
__global__ __launch_bounds__(256) void gemm_s1_kernel(
    const unsigned short* xr, const unsigned short* xk, const unsigned short* xv,
    const unsigned short* xw, const unsigned short* xa, const unsigned short* xg,
    const unsigned short* wtA, const unsigned short* wtB, const unsigned short* wtC,
    const unsigned short* wt_a1, const unsigned short* wt_v1,
    const unsigned short* wt_g1, const unsigned short* wt_w1,
    unsigned short* b_r, unsigned short* pk_bf, unsigned short* b_v,
    unsigned short* h_cat)
{
    const int nt = blockIdx.x;
    const int bm0 = blockIdx.y * GBM;
    const unsigned short* A; const unsigned short* WT;
    unsigned short* outp = nullptr; unsigned short* outh = nullptr;
    int Nc = 1024, nb = 0, ostr = 1, ooff = 0, hoff = 0, post = 0;
    if (nt < 16)      { A = xr; WT = wtC; outp = b_r; nb = nt; }
    else if (nt < 32) { A = xk; WT = wtA; outp = pk_bf; ostr = 4; ooff = 1; nb = nt - 16; }
    else if (nt < 48) { A = xv; WT = wtB; outp = b_v; nb = nt - 32; }
    else if (nt == 48){ A = xa; WT = wt_a1; outh = h_cat; hoff = 0;   Nc = 64; }
    else if (nt == 49){ A = xv; WT = wt_v1; outh = h_cat; hoff = 64;  Nc = 32; }
    else if (nt < 53) { A = xg; WT = wt_g1; outh = h_cat; hoff = 96;  Nc = 160; nb = nt - 50; post = 2; }
    else              { A = xw; WT = wt_w1; outh = h_cat; hoff = 256; Nc = 64; post = 1; }
    gemm_core(A, 1024, WT, 1024, Nc, nb * 64, bm0, outp, ostr, ooff, outh, hoff, post);
}

// ---------------- stage-2: 4 GEMMs in one launch (A = h_cat) ----------------
__global__ __launch_bounds__(256) void gemm_s2_kernel(
    const unsigned short* __restrict__ h_cat,
    const unsigned short* wt_a2, const unsigned short* wt_v2,
    const unsigned short* wt_g2, const unsigned short* wt_w2,
    unsigned short* pk_bf, unsigned short* b_g)
{
    const int g = blockIdx.x >> 4;
    const int nb = blockIdx.x & 15;
    const int bm0 = blockIdx.y * GBM;
    const unsigned short* WT;
    unsigned short* outp; int K, aoff, ostr, ooff;
    if      (g == 0) { WT = wt_a2; K = 64;  aoff = 0;   outp = pk_bf; ostr = 4; ooff = 2; }
    else if (g == 1) { WT = wt_v2; K = 32;  aoff = 64;  outp = pk_bf; ostr = 4; ooff = 3; }
    else if (g == 2) { WT = wt_g2; K = 160; aoff = 96;  outp = b_g;   ostr = 1; ooff = 0; }
    else             { WT = wt_w2; K = 64;  aoff = 256; outp = pk_bf; ostr = 4; ooff = 0; }
    gemm_core(h_cat + aoff, 320, WT, K, 1024, nb * 64, bm0, outp, ostr, ooff, nullptr, 0, 0);
}

// ---------------- final GEMM: out = y_bf @ W_o + residual (f32 out) ----------------
__global__ __launch_bounds__(256) void gemm_final_kernel(
    const unsigned short* __restrict__ Y, const unsigned short* __restrict__ WT,
    const float* __restrict__ addend, float* __restrict__ out)
{
    const int K = 1024;
    __shared__ unsigned short As[GBM][LDK];
    __shared__ unsigned short Bs[GBN][LDK];

    const int tid = threadIdx.x;
    const int lane = tid & 63;
    const int wid = tid >> 6;
    const int wr = wid >> 1, wc = wid & 1;
    const int l15 = lane & 15, l4 = lane >> 4;
    const int bm0 = blockIdx.y * GBM;
    const int bn0 = blockIdx.x * GBN;
    const int ar = tid >> 2;
    const int as = (tid & 3) << 4;
    const int row = bm0 + ar;
    const int brn = tid >> 2;
    const int bks = (tid & 3) << 4;

    const int ra0 = wr * 32 + l15, ra1 = wr * 32 + 16 + l15;
    const int rb0 = wc * 32 + l15, rb1 = wc * 32 + 16 + l15;

    f32x4 acc[2][2] = {};

    for (int k0 = 0; k0 < K; k0 += GBK) {
#pragma unroll
        for (int i = 0; i < 2; ++i) {
            const int kk = as + 8 * i;
            *(ushortx8*)&As[ar][SW(ar, kk)] =
                *(const ushortx8*)(Y + (size_t)row * 1024 + k0 + kk);
        }
#pragma unroll
        for (int i = 0; i < 2; ++i) {
            const int kk = bks + 8 * i;
            *(ushortx8*)&Bs[brn][SW(brn, kk)] =
                *(const ushortx8*)(WT + (size_t)(bn0 + brn) * K + k0 + kk);
        }
        __syncthreads();
#pragma unroll
        for (int ks = 0; ks < 2; ++ks) {
            const int cc = ks * 32 + l4 * 8;
            bf16x8 af0 = *(const bf16x8*)&As[ra0][SW(ra0, cc)];
            bf16x8 af1 = *(const bf16x8*)&As[ra1][SW(ra1, cc)];
            bf16x8 bg0 = *(const bf16x8*)&Bs[rb0][SW(rb0, cc)];
            bf16x8 bg1 = *(const bf16x8*)&Bs[rb1][SW(rb1, cc)];
            acc[0][0] = __builtin_amdgcn_mfma_f32_16x16x32_bf16(af0, bg0, acc[0][0], 0, 0, 0);
            acc[0][1] = __builtin_amdgcn_mfma_f32_16x16x32_bf16(af0, bg1, acc[0][1], 0, 0, 0);
            acc[1][0] = __builtin_amdgcn_mfma_f32_16x16x32_bf16(af1, bg0, acc[1][0], 0, 0, 0);
            acc[1][1] = __builtin_amdgcn_mfma_f32_16x16x32_bf16(af1, bg1, acc[1][1], 0, 0, 0);
        }
        __syncthreads();
    }

#pragma unroll
    for (int fi = 0; fi < 2; ++fi)
#pragma unroll
        for (int fj = 0; fj < 2; ++fj) {
            const int ocol = bn0 + wc * 32 + fj * 16 + l15;
#pragma unroll
            for (int p = 0; p < 4; ++p) {
                const int orow = bm0 + wr * 32 + fi * 16 + l4 * 4 + p;
                out[(size_t)orow * 1024 + ocol] =
                    acc[fi][fj][p] + addend[(size_t)orow * 1024 + ocol];
            }
        }
}

// ---------------- chunked-scan PREP (stage3 folded in, MFMA-ized) ----------------
// Per block: one (bh, chunk of 32 steps). 4 waves.
// Recurrence: S_t = S_{t-1}(diag(ew_t) + aa_t bb_t^T) + v_t ko_t^T.
// Outputs per chunk: Gt[t][n], LRt[n][k'], VcT[n][vi] f32, Wl[n], Oi[t][vi].
__global__ __launch_bounds__(256) void chunk_prep_kernel(
    const unsigned short* __restrict__ pk_bf,
    const unsigned short* __restrict__ b_r,
    unsigned short* __restrict__ b_v,
    const float* __restrict__ v_first,
    const float* w0, const float* a0, const float* v0,
    const float* k_k, const float* k_a, const float* r_k,
    float* __restrict__ TB,
    unsigned short* __restrict__ Gt, unsigned short* __restrict__ LRt,
    float* __restrict__ Vc, float* __restrict__ Wl,
    unsigned short* __restrict__ Oi)
{
    // ---- LDS arena (60800 B) with phase overlays ----
    __shared__ __align__(16) char smem[60800];
    unsigned short (*tB)[72]  = (unsigned short (*)[72])(smem + 0);
    unsigned short (*tK)[72]  = (unsigned short (*)[72])(smem + 4608);
    unsigned short (*tR)[72]  = (unsigned short (*)[72])(smem + 9216);
    unsigned short (*tBT)[40] = (unsigned short (*)[40])(smem + 13824);
    unsigned short (*VlT)[40] = (unsigned short (*)[40])(smem + 18944);
    unsigned short (*egT)[40] = (unsigned short (*)[40])(smem + 24064);
    float (*W32s)[66]         = (float (*)[66])(smem + 26624);
    float (*fg)[33]           = (float (*)[33])(smem + 35072);
    unsigned short (*tA)[72]  = (unsigned short (*)[72])(smem + 39296); // dead after F
    float (*cg)[33]           = (float (*)[33])(smem + 43904);          // dead after F
    unsigned short (*ZB)[40]  = (unsigned short (*)[40])(smem + 39296); // over tA
    unsigned short (*DhB)[40] = (unsigned short (*)[40])(smem + 44416); // over cg
    float (*dg)[33]           = (float (*)[33])(smem + 48128);          // dead after F2
    unsigned short (*fT)[40]  = (unsigned short (*)[40])(smem + 48128); // over dg
    float* EWZ                = (float*)(smem + 52352);                 // dead after F2
    unsigned short (*KtT)[40] = (unsigned short (*)[40])(smem + 52352); // over EWZ

    const int tid = threadIdx.x;
    const int lane = tid & 63;
    const int w = tid >> 6;
    const int l15 = lane & 15, l4 = lane >> 4;
    const int bhc = blockIdx.x;
    const int bh = bhc >> 5, ck = bhc & 31;
    const int b = bh >> 4, h = bh & 15;
    const int cglob = h * 64 + lane;

    // ---- Phase A: loads + stage3 elementwise + raw stores ----
    const float kkc = k_k[cglob], kac = k_a[cglob];
    const float a0c = a0[cglob], v0c = v0[cglob];
    const float w0c = w0[cglob], rkc = r_k[cglob];
#pragma unroll
    for (int q = 0; q < 8; ++q) {
        const int tq = w * 8 + q;
        const int row = b * 1024 + ck * 32 + tq;
        const size_t gi = (size_t)row * 1024 + cglob;
        const ushortx4 pk = *(const ushortx4*)(pk_bf + gi * 4);
        const float kl = bf2f(pk.y);
        const float kkv = kl * kkc;
        const float ss = wred64(kkv * kkv);
        const float kkn = kkv / fmaxf(sqrtf(ss), 1e-12f);
        const float a = 1.0f / (1.0f + expf(-(a0c + bf2f(pk.z))));
        const float u = w0c + bf2f(pk.x);
        const float ew = expf(-expf(-log1pf(expf(-u)) - 0.5f));
        const float sv = 1.0f / (1.0f + expf(-(v0c + bf2f(pk.w))));
        const float vl = bf2f(b_v[gi]);
        const float v = fmaf(v_first[gi] - vl, sv, vl);
        const float ko = kl * (1.0f + (a - 1.0f) * kac);
        const unsigned short rbf = b_r[gi];
        const float r1f = bf2f(rbf);
        const unsigned short vbf = f2bf(v);
        b_v[gi] = vbf;

        const float t3 = wred64(r1f * ko * rkc);
        if (lane == 0) TB[bh * 1024 + ck * 32 + tq] = t3;

        EWZ[tq * 64 + lane] = ew;
        tA[tq][lane] = f2bf(-kkn);
        tB[tq][lane] = f2bf(kkn * a);
        tK[tq][lane] = f2bf(ko);
        tR[tq][lane] = rbf;
        VlT[lane][tq] = vbf;
    }
    __syncthreads();

    // ---- Phase B: decay cumprods (wave 0) ----
    if (w == 0) {
        float run = 1.0f;
        for (int t = 0; t < 32; ++t) {
            run *= EWZ[t * 64 + lane];
            W32s[t][lane] = run;
        }
    }
    __syncthreads();

    // ---- Phase C: tildes in place + tBT ----
#pragma unroll
    for (int q = 0; q < 8; ++q) {
        const int tq = w * 8 + q;
        const float Wt = W32s[tq][lane];
        const float Wm1 = tq ? W32s[tq - 1][lane] : 1.0f;
        const float iw = 1.0f / Wt;
        tA[tq][lane] = f2bf(bf2f(tA[tq][lane]) * Wm1);
        const unsigned short tb = f2bf(bf2f(tB[tq][lane]) * iw);
        tB[tq][lane] = tb;
        tBT[lane][tq] = tb;
        tK[tq][lane] = f2bf(bf2f(tK[tq][lane]) * iw);
        tR[tq][lane] = f2bf(bf2f(tR[tq][lane]) * Wt);
    }
    __syncthreads();

    // ---- Phase D: four 32x32 Grams via MFMA (one per wave) ----
    {
        const unsigned short (*Am)[72] = (w == 0 || w == 2) ? tB : tK;
        const unsigned short (*Bm)[72] = (w < 2) ? tA : tR;
        f32x4 gacc[2][2] = {};
#pragma unroll
        for (int kh = 0; kh < 2; ++kh) {
            const int cc = kh * 32 + l4 * 8;
            bf16x8 ax0 = *(const bf16x8*)&Am[l15][cc];
            bf16x8 ax1 = *(const bf16x8*)&Am[16 + l15][cc];
            bf16x8 bx0 = *(const bf16x8*)&Bm[l15][cc];
            bf16x8 bx1 = *(const bf16x8*)&Bm[16 + l15][cc];
            gacc[0][0] = __builtin_amdgcn_mfma_f32_16x16x32_bf16(ax0, bx0, gacc[0][0], 0, 0, 0);
            gacc[0][1] = __builtin_amdgcn_mfma_f32_16x16x32_bf16(ax0, bx1, gacc[0][1], 0, 0, 0);
            gacc[1][0] = __builtin_amdgcn_mfma_f32_16x16x32_bf16(ax1, bx0, gacc[1][0], 0, 0, 0);
            gacc[1][1] = __builtin_amdgcn_mfma_f32_16x16x32_bf16(ax1, bx1, gacc[1][1], 0, 0, 0);
        }
#pragma unroll
        for (int mt = 0; mt < 2; ++mt)
#pragma unroll
            for (int nt = 0; nt < 2; ++nt) {
                const int col = nt * 16 + l15;
                if (w == 2) {   // eg[i][t] -> egT[t][i]
                    ushortx4 st;
#pragma unroll
                    for (int p = 0; p < 4; ++p) st[p] = f2bf(gacc[mt][nt][p]);
                    *(ushortx4*)&egT[col][mt * 16 + l4 * 4] = st;
                } else {
#pragma unroll
                    for (int p = 0; p < 4; ++p) {
                        const int rw = mt * 16 + l4 * 4 + p;
                        if (w == 0) cg[rw][col] = gacc[mt][nt][p];
                        else if (w == 1) dg[rw][col] = gacc[mt][nt][p];
                        else fg[rw][col] = gacc[mt][nt][p];
                    }
                }
            }
    }
    __syncthreads();

    // ---- Phase E: zero invalid triangles ----
#pragma unroll
    for (int p = 0; p < 4; ++p) {
        const int idx = tid * 4 + p;
        const int r_ = idx >> 5, c_ = idx & 31;
        if (r_ >= c_) cg[r_][c_] = 0.0f;     // keep j<i
        if (c_ <= r_) dg[r_][c_] = 0.0f;     // keep j>i
        if (r_ > c_) fg[r_][c_] = 0.0f;      // keep i<=t
        if (c_ > r_) egT[r_][c_] = 0;        // egT[t][i]: keep i<=t
    }
    __syncthreads();

    // ---- Phase F: triangular recurrences (serial, conflict-free) ----
    if (w == 0) {
        for (int i = 0; i < 32; ++i) {       // Z[n][i]
            float val = bf2f(tA[i][lane]);
            for (int j = 0; j < i; ++j) val += cg[j][i] * EWZ[lane * 33 + j];
            EWZ[lane * 33 + i] = val;
        }
    } else if (w == 1 && lane < 32) {
        for (int t = 0; t < 32; ++t) {       // Dhat in place over dg
            float val = dg[lane][t];
            for (int j = 0; j < t; ++j) val += cg[j][t] * dg[lane][j];
            dg[lane][t] = val;
        }
    }
    __syncthreads();

    // ---- Phase F2: bf16 copies (DhB over cg, ZB over tA) ----
#pragma unroll
    for (int p = 0; p < 4; ++p) {
        const int idx = tid * 4 + p;
        DhB[idx >> 5][idx & 31] = f2bf(dg[idx >> 5][idx & 31]);
    }
#pragma unroll
    for (int p = 0; p < 8; ++p) {
        const int idx = tid * 8 + p;
        ZB[idx >> 5][idx & 31] = f2bf(EWZ[(idx >> 5) * 33 + (idx & 31)]);
    }
    __syncthreads();

    const size_t cb2048 = (size_t)bhc * 2048;
    const size_t cb4096 = (size_t)bhc * 4096;

    // ---- Phase G-a ----
    if (w == 0) {
        // f[i][t] = fg + Dhat@eg -> fT[t][i]
#pragma unroll
        for (int mt = 0; mt < 2; ++mt)
#pragma unroll
            for (int nt = 0; nt < 2; ++nt) {
                f32x4 cacc;
#pragma unroll
                for (int p = 0; p < 4; ++p) cacc[p] = fg[mt * 16 + l4 * 4 + p][nt * 16 + l15];
                bf16x8 ax = *(const bf16x8*)&DhB[mt * 16 + l15][l4 * 8];
                bf16x8 bx = *(const bf16x8*)&egT[nt * 16 + l15][l4 * 8];
                cacc = __builtin_amdgcn_mfma_f32_16x16x32_bf16(ax, bx, cacc, 0, 0, 0);
                ushortx4 st;
#pragma unroll
                for (int p = 0; p < 4; ++p) st[p] = f2bf(cacc[p]);
                *(ushortx4*)&fT[nt * 16 + l15][mt * 16 + l4 * 4] = st;
            }
    } else if (w == 1) {
        // Ktilde[i][n] = (Khat + Dhat@Btilde)*W31[n] -> KtT[n][i]
#pragma unroll
        for (int mt = 0; mt < 2; ++mt)
#pragma unroll
            for (int nt = 0; nt < 4; ++nt) {
                bf16x8 ax = *(const bf16x8*)&DhB[mt * 16 + l15][l4 * 8];
                bf16x8 bx = *(const bf16x8*)&tBT[nt * 16 + l15][l4 * 8];
                f32x4 cacc = {};
                cacc = __builtin_amdgcn_mfma_f32_16x16x32_bf16(ax, bx, cacc, 0, 0, 0);
                const int col = nt * 16 + l15;
                const float w31c = W32s[31][col];
                ushortx4 st;
#pragma unroll
                for (int p = 0; p < 4; ++p) {
                    const int rw = mt * 16 + l4 * 4 + p;
                    st[p] = f2bf((cacc[p] + bf2f(tK[rw][col])) * w31c);
                }
                *(ushortx4*)&KtT[col][mt * 16 + l4 * 4] = st;
            }
    } else if (w == 2) {
        // LRt[n][k'] = W31[n] * sum_i tB[i][n] Z[k'][i]
#pragma unroll
        for (int mt = 0; mt < 4; ++mt)
#pragma unroll
            for (int nt = 0; nt < 4; ++nt) {
                bf16x8 ax = *(const bf16x8*)&tBT[mt * 16 + l15][l4 * 8];
                bf16x8 bx = *(const bf16x8*)&ZB[nt * 16 + l15][l4 * 8];
                f32x4 cacc = {};
                cacc = __builtin_amdgcn_mfma_f32_16x16x32_bf16(ax, bx, cacc, 0, 0, 0);
                const int kcol = nt * 16 + l15;
#pragma unroll
                for (int p = 0; p < 4; ++p) {
                    const int n_ = mt * 16 + l4 * 4 + p;
                    LRt[cb4096 + n_ * 64 + kcol] = f2bf(cacc[p] * W32s[31][n_]);
                }
            }
    } else {
        // Gt[t][n] = tR + sum_i eg[i][t] Z[n][i]
#pragma unroll
        for (int mt = 0; mt < 2; ++mt)
#pragma unroll
            for (int nt = 0; nt < 4; ++nt) {
                bf16x8 ax = *(const bf16x8*)&egT[mt * 16 + l15][l4 * 8];
                bf16x8 bx = *(const bf16x8*)&ZB[nt * 16 + l15][l4 * 8];
                f32x4 cacc = {};
                cacc = __builtin_amdgcn_mfma_f32_16x16x32_bf16(ax, bx, cacc, 0, 0, 0);
                const int ncol = nt * 16 + l15;
#pragma unroll
                for (int p = 0; p < 4; ++p) {
                    const int t_ = mt * 16 + l4 * 4 + p;
                    Gt[cb2048 + t_ * 64 + ncol] = f2bf(cacc[p] + bf2f(tR[t_][ncol]));
                }
            }
    }
    __syncthreads();

    // ---- Phase G-b ----
    if (w < 2) {
        // Oi[t][vi] = sum_i f[i][t] Vl[i][vi]; wave w takes vi-tiles {2w, 2w+1}
#pragma unroll
        for (int mt = 0; mt < 2; ++mt)
#pragma unroll
            for (int ntl = 0; ntl < 2; ++ntl) {
                const int nt = w * 2 + ntl;
                bf16x8 ax = *(const bf16x8*)&fT[mt * 16 + l15][l4 * 8];
                bf16x8 bx = *(const bf16x8*)&VlT[nt * 16 + l15][l4 * 8];
                f32x4 cacc = {};
                cacc = __builtin_amdgcn_mfma_f32_16x16x32_bf16(ax, bx, cacc, 0, 0, 0);
                const int vcol = nt * 16 + l15;
#pragma unroll
                for (int p = 0; p < 4; ++p) {
                    const int t_ = mt * 16 + l4 * 4 + p;
                    Oi[cb2048 + t_ * 64 + vcol] = f2bf(cacc[p]);
                }
            }
    } else {
        // VcT[n][vi] = sum_i Vl[i][vi] Ktilde[i][n]; wave takes vi-tiles {2(w-2), +1}
#pragma unroll
        for (int mtl = 0; mtl < 2; ++mtl)
#pragma unroll
            for (int nt = 0; nt < 4; ++nt) {
                const int mt = (w - 2) * 2 + mtl;
                bf16x8 ax = *(const bf16x8*)&VlT[mt * 16 + l15][l4 * 8];
                bf16x8 bx = *(const bf16x8*)&KtT[nt * 16 + l15][l4 * 8];
                f32x4 cacc = {};
                cacc = __builtin_amdgcn_mfma_f32_16x16x32_bf16(ax, bx, cacc, 0, 0, 0);
                const int ncol = nt * 16 + l15;
                float4 st = make_float4(cacc[0], cacc[1], cacc[2], cacc[3]);
                *(float4*)&Vc[cb4096 + (size_t)ncol * 64 + mt * 16 + l4 * 4] = st;
            }
    }
    if (tid < 64) Wl[(size_t)bhc * 64 + tid] = W32s[31][tid];
}

// ---------------- chunked-scan SEQ: 128 blocks (bh x 4 vi-groups), 1 wave each ----
struct SeqRegs {
    bf16x8 g[4];
    bf16x8 lr[8];
    float4 vc[4];
    float wl[4];
    ushortx4 oi[2];
};

__device__ __forceinline__ void load_chunk(
    SeqRegs& R,
    const unsigned short* __restrict__ gt, const unsigned short* __restrict__ lr,
    const float* __restrict__ vct, const float* __restrict__ wlp,
    const unsigned short* __restrict__ oi, int l15, int l4, int vg)
{
#pragma unroll
    for (int tt = 0; tt < 2; ++tt) {
        R.g[tt * 2 + 0] = *(const bf16x8*)&gt[(tt * 16 + l15) * 64 + l4 * 8];
        R.g[tt * 2 + 1] = *(const bf16x8*)&gt[(tt * 16 + l15) * 64 + 32 + l4 * 8];
        R.oi[tt] = *(const ushortx4*)&oi[(tt * 16 + l15) * 64 + vg * 16 + l4 * 4];
    }
#pragma unroll
    for (int nt = 0; nt < 4; ++nt) {
        R.lr[nt * 2 + 0] = *(const bf16x8*)&lr[(nt * 16 + l15) * 64 + l4 * 8];
        R.lr[nt * 2 + 1] = *(const bf16x8*)&lr[(nt * 16 + l15) * 64 + 32 + l4 * 8];
        R.vc[nt] = *(const float4*)&vct[(nt * 16 + l15) * 64 + vg * 16 + l4 * 4];
        R.wl[nt] = wlp[nt * 16 + l15];
    }
}

__device__ __forceinline__ void seq_step(
    f32x4* sC, const SeqRegs& R, unsigned short (*Sst)[80],
    unsigned short* __restrict__ o, int b, int h, int c, int vg, int l15, int l4)
{
    // master S (C/D layout) -> LDS bf16 (A layout source); wave-private, no barrier
#pragma unroll
    for (int nt = 0; nt < 4; ++nt)
#pragma unroll
        for (int p = 0; p < 4; ++p)
            Sst[l4 * 4 + p][nt * 16 + l15] = f2bf(sC[nt][p]);
    __builtin_amdgcn_wave_barrier();
    bf16x8 a0 = *(const bf16x8*)&Sst[l15][l4 * 8];
    bf16x8 a1 = *(const bf16x8*)&Sst[l15][32 + l4 * 8];
    __builtin_amdgcn_wave_barrier();

    f32x4 oacc[2] = {};
#pragma unroll
    for (int tt = 0; tt < 2; ++tt) {
        oacc[tt] = __builtin_amdgcn_mfma_f32_16x16x32_bf16(a0, R.g[tt * 2 + 0], oacc[tt], 0, 0, 0);
        oacc[tt] = __builtin_amdgcn_mfma_f32_16x16x32_bf16(a1, R.g[tt * 2 + 1], oacc[tt], 0, 0, 0);
    }
    f32x4 lac[4] = {};
#pragma unroll
    for (int nt = 0; nt < 4; ++nt) {
        lac[nt] = __builtin_amdgcn_mfma_f32_16x16x32_bf16(a0, R.lr[nt * 2 + 0], lac[nt], 0, 0, 0);
        lac[nt] = __builtin_amdgcn_mfma_f32_16x16x32_bf16(a1, R.lr[nt * 2 + 1], lac[nt], 0, 0, 0);
    }

#pragma unroll
    for (int nt = 0; nt < 4; ++nt) {
        const float wlv = R.wl[nt];
#pragma unroll
        for (int p = 0; p < 4; ++p)
            sC[nt][p] = sC[nt][p] * wlv + lac[nt][p] + R.vc[nt][p];
    }

#pragma unroll
    for (int tt = 0; tt < 2; ++tt) {
        const int trow = b * 1024 + c * 32 + tt * 16 + l15;
        ushortx4 ov;
        ov.x = f2bf(oacc[tt][0] + bf2f(R.oi[tt].x));
        ov.y = f2bf(oacc[tt][1] + bf2f(R.oi[tt].y));
        ov.z = f2bf(oacc[tt][2] + bf2f(R.oi[tt].z));
        ov.w = f2bf(oacc[tt][3] + bf2f(R.oi[tt].w));
        *(ushortx4*)(o + (size_t)trow * 1024 + h * 64 + vg * 16 + l4 * 4) = ov;
    }
}

__global__ __launch_bounds__(64) void chunk_seq_kernel(
    const unsigned short* __restrict__ Gt, const unsigned short* __restrict__ LRt,
    const float* __restrict__ VcT, const float* __restrict__ Wl,
    const unsigned short* __restrict__ Oi, unsigned short* __restrict__ o)
{
    __shared__ unsigned short Sst[16][80];
    const int lane = threadIdx.x & 63;
    const int bid = blockIdx.x;
    const int bh = bid >> 2, vg = bid & 3;
    const int b = bh >> 4, h = bh & 15;
    const int l15 = lane & 15, l4 = lane >> 4;

    const size_t cbase = (size_t)bh * 32;
    const unsigned short* gt = Gt + cbase * 2048;
    const unsigned short* lr = LRt + cbase * 4096;
    const float* vct = VcT + cbase * 4096;
    const float* wlp = Wl + cbase * 64;
    const unsigned short* oi = Oi + cbase * 2048;

    f32x4 sC[4] = {};
    SeqRegs RA, RB;
    load_chunk(RA, gt, lr, vct, wlp, oi, l15, l4, vg);

    for (int cc = 0; cc < 16; ++cc) {
        const int c0 = cc * 2, c1 = cc * 2 + 1;
        load_chunk(RB, gt + (size_t)c1 * 2048, lr + (size_t)c1 * 4096,
                   vct + (size_t)c1 * 4096, wlp + (size_t)c1 * 64,
                   oi + (size_t)c1 * 2048, l15, l4, vg);
        seq_step(sC, RA, Sst, o, b, h, c0, vg, l15, l4);
        const int c2 = (c1 + 1 < 32) ? c1 + 1 : 31;
        load_chunk(RA, gt + (size_t)c2 * 2048, lr + (size_t)c2 * 4096,
                   vct + (size_t)c2 * 4096, wlp + (size_t)c2 * 64,
                   oi + (size_t)c2 * 2048, l15, l4, vg);
        seq_step(sC, RB, Sst, o, b, h, c1, vg, l15, l4);
    }
}

// ---------------- groupnorm + bonus + gate (bf16 in, bf16 y out) ----------------
__global__ __launch_bounds__(256) void post_kernel(
    const unsigned short* o, const unsigned short* v, const unsigned short* g,
    const float* __restrict__ TB,
    const float* ln_w, const float* ln_b,
    unsigned short* y)
{
    const int gw = (blockIdx.x * blockDim.x + threadIdx.x) >> 6;
    const int lane = threadIdx.x & 63;
    const int row = gw >> 4;
    const int h = gw & 15;
    const int c = h * N_DIM + lane;
    const size_t idx = (size_t)row * C_DIM + c;
    const int b = row >> 10;
    const int t = row & 1023;

    const float oo = bf2f(o[idx]);
    float s1 = oo, s2 = oo * oo;
#pragma unroll
    for (int m = 32; m; m >>= 1) {
        s1 += __shfl_xor(s1, m);
        s2 += __shfl_xor(s2, m);
    }
    const float mu = s1 * (1.0f / 64.0f);
    const float var = s2 * (1.0f / 64.0f) - mu * mu;
    float yv = (oo - mu) * rsqrtf(var + 0.00064f);
    yv = yv * ln_w[c] + ln_b[c];

    yv += TB[(b * 16 + h) * 1024 + t] * bf2f(v[idx]);
    y[idx] = f2bf(yv * bf2f(g[idx]));
}

extern "C" void kernel_launch(void* const* d_in, const int* in_sizes, int n_in,
                              void* d_out, int out_size, void* d_ws, size_t ws_size,
                              hipStream_t stream) {
    (void)in_sizes; (void)n_in; (void)out_size; (void)ws_size;

    const float* residual = (const float*)d_in[0];
    const float* x        = (const float*)d_in[1];
    const float* v_first  = (const float*)d_in[2];
    const float* mr = (const float*)d_in[6];
    const float* mw = (const float*)d_in[7];
    const float* mk = (const float*)d_in[8];
    const float* mv = (const float*)d_in[9];
    const float* ma = (const float*)d_in[10];
    const float* mg = (const float*)d_in[11];
    const float* w0 = (const float*)d_in[12];
    const float* w1 = (const float*)d_in[13];
    const float* w2 = (const float*)d_in[14];
    const float* a0 = (const float*)d_in[15];
    const float* a1 = (const float*)d_in[16];
    const float* a2 = (const float*)d_in[17];
    const float* v0 = (const float*)d_in[18];
    const float* v1 = (const float*)d_in[19];
    const float* v2 = (const float*)d_in[20];
    const float* g1 = (const float*)d_in[21];
    const float* g2 = (const float*)d_in[22];
    const float* k_k = (const float*)d_in[23];
    const float* k_a = (const float*)d_in[24];
    const float* r_k = (const float*)d_in[25];
    const float* W_r = (const float*)d_in[26];
    const float* W_k = (const float*)d_in[27];
    const float* W_v = (const float*)d_in[28];
    const float* W_o = (const float*)d_in[29];
    const float* ln_w = (const float*)d_in[30];
    const float* ln_b = (const float*)d_in[31];

    float* out = (float*)d_out;
    char* wsb = (char*)d_ws;

    // ---- workspace layout (bytes); max end 69,730,304 (proven safe) ----
    unsigned short* xr = (unsigned short*)(wsb + 0);
    unsigned short* xk = (unsigned short*)(wsb + 4194304);
    unsigned short* xv = (unsigned short*)(wsb + 8388608);
    unsigned short* xw = (unsigned short*)(wsb + 12582912);
    unsigned short* xa = (unsigned short*)(wsb + 16777216);
    unsigned short* xg = (unsigned short*)(wsb + 20971520);     // ends 25,165,824
    float* Vc          = (float*)(wsb + 0);                     // over xr..xv (post-s1)  VcT[n][vi]
    unsigned short* Gt = (unsigned short*)(wsb + 16777216);     // over xa
    unsigned short* Oi = (unsigned short*)(wsb + 20971520);     // over xg
    unsigned short* pk_bf = (unsigned short*)(wsb + 25165824);  // 16 MiB (dead after prep)
    unsigned short* wtD = (unsigned short*)(wsb + 25165824);    // 2 MiB (after prep)
    unsigned short* y_bf = (unsigned short*)(wsb + 27262976);   // 4 MiB
    unsigned short* b_r = (unsigned short*)(wsb + 41943040);
    unsigned short* b_v = (unsigned short*)(wsb + 46137344);
    unsigned short* b_o = (unsigned short*)(wsb + 50331648);
    unsigned short* b_g = (unsigned short*)(wsb + 54525952);
    unsigned short* h_cat = (unsigned short*)(wsb + 58720256);
    unsigned short* wt_a1 = (unsigned short*)(wsb + 60293120);
    unsigned short* wt_v1 = (unsigned short*)(wsb + 60424192);
    unsigned short* wt_g1 = (unsigned short*)(wsb + 60489728);
    unsigned short* wt_a2 = (unsigned short*)(wsb + 60817408);
    unsigned short* wt_v2 = (unsigned short*)(wsb + 60948480);
    unsigned short* wt_g2 = (unsigned short*)(wsb + 61014016);
    unsigned short* wt_w1 = (unsigned short*)(wsb + 61341696);
    unsigned short* wt_w2 = (unsigned short*)(wsb + 61472768);
    unsigned short* wtA = (unsigned short*)(wsb + 61603840);
    unsigned short* wtB = (unsigned short*)(wsb + 63700992);
    unsigned short* wtC = (unsigned short*)(wsb + 65798144);    // ends 67,895,296
    unsigned short* LRt = (unsigned short*)(wsb + 60030976);    // 8 MiB over dead wts
    float* Wl = (float*)(wsb + 68419584);
    float* TB = (float*)(wsb + 68681728);

    const dim3 blk(256);
    const dim3 tblk(32, 8);

    // 1) premix
    premix_kernel<<<dim3(1024), blk, 0, stream>>>(
        x, mr, mk, mv, mw, ma, mg, xr, xk, xv, xw, xa, xg);

    // 2) transpose W_k, W_v, W_r + all small weights
    trans_all_kernel<<<dim3(3712), tblk, 0, stream>>>(
        W_k, W_v, W_r, w1, a1, v1, g1, a2, v2, g2, w2,
        wtA, wtB, wtC, wt_w1, wt_a1, wt_v1, wt_g1, wt_a2, wt_v2, wt_g2, wt_w2);

    // 3) stage-1: r, k, v, a1, v1, g1, w1
    gemm_s1_kernel<<<dim3(54, 32), blk, 0, stream>>>(
        xr, xk, xv, xw, xa, xg, wtA, wtB, wtC,
        wt_a1, wt_v1, wt_g1, wt_w1, b_r, pk_bf, b_v, h_cat);

    // 4) stage-2: a2, v2, g2, w2
    gemm_s2_kernel<<<dim3(64, 32), blk, 0, stream>>>(
        h_cat, wt_a2, wt_v2, wt_g2, wt_w2, pk_bf, b_g);

    // 5) chunk prep (stage3 folded in, MFMA-ized WY transform)
    chunk_prep_kernel<<<dim3(1024), blk, 0, stream>>>(
        pk_bf, b_r, b_v, v_first, w0, a0, v0, k_k, k_a, r_k,
        TB, Gt, LRt, Vc, Wl, Oi);

    // 6) W_o transpose (over dead pk_bf head)
    wtrans_kernel<<<dim3(32, 32), tblk, 0, stream>>>(W_o, wtD);

    // 7) sequential chunk scan (MFMA, vi-parallel, register-pipelined)
    chunk_seq_kernel<<<dim3(128), dim3(64), 0, stream>>>(Gt, LRt, Vc, Wl, Oi, b_o);

    // 8) groupnorm + bonus + gate
    post_kernel<<<dim3(8192), blk, 0, stream>>>(
        b_o, b_v, b_g, TB, ln_w, ln_b, y_bf);

    // 9) output projection + residual
    gemm_final_kernel<<<dim3(16, 32), blk, 0, stream>>>(y_bf, wtD, residual, out);
}